// Round 2
// baseline (7285.255 us; speedup 1.0000x reference)
//
#include <hip/hip_runtime.h>
#include <cstdint>

// Problem constants (MicroCortexMLA): B=2, S=2048, H=2048, NH=16,
// NOPE=128, ROPE=64, VD=128, QLORA=1536, KVLORA=512, theta=1e6, eps=1e-6
// Harness dtypes: all float inputs are FP32 (reference uses jnp.float32);
// position_ids int32; output FP32. We convert to bf16 in ws for MFMA compute.
#define S_LEN 2048
#define NH_N  16

typedef short s16x8 __attribute__((ext_vector_type(8)));
typedef unsigned short u16x8 __attribute__((ext_vector_type(8)));
typedef float f32x4 __attribute__((ext_vector_type(4)));

__device__ __forceinline__ float b2f(unsigned short u) {
    return __uint_as_float(((uint32_t)u) << 16);
}
// round-to-nearest-even f32 -> bf16
__device__ __forceinline__ unsigned short f2b(float f) {
    uint32_t x = __float_as_uint(f);
    x += 0x7fffu + ((x >> 16) & 1u);
    return (unsigned short)(x >> 16);
}

__device__ __forceinline__ void cstore(unsigned short* p, float v) { *p = f2b(v); }
__device__ __forceinline__ void cstore(float* p, float v) { *p = v; }

// ---------------------------------------------------------------------------
// fp32 -> bf16 conversion, vectorized x4, grid-stride. n % 4 == 0.
// ---------------------------------------------------------------------------
__global__ __launch_bounds__(256) void f32_to_bf16(const float* __restrict__ in,
                                                   unsigned short* __restrict__ out,
                                                   long n)
{
    const long nv = n >> 2;
    long i = (long)blockIdx.x * blockDim.x + threadIdx.x;
    const long stride = (long)gridDim.x * blockDim.x;
    for (; i < nv; i += stride) {
        float4 v = ((const float4*)in)[i];
        ushort4 o;
        o.x = f2b(v.x); o.y = f2b(v.y); o.z = f2b(v.z); o.w = f2b(v.w);
        ((ushort4*)out)[i] = o;
    }
}

// ---------------------------------------------------------------------------
// C = A @ B^T   (A: MxK row-major, B: NxK row-major, C: MxN row-major)
// A,B bf16; C bf16 or fp32 (template). block = 256 thr = 4 waves; block tile
// 64x64; wave computes 16(m) x 64(n) via mfma_f32_16x16x32_bf16.
// Fragment layouts (HW-verified on gfx950):
//   A/B frag: elem (lane&15, quad*8+j)  -> one 16B contiguous load per frag
//   D frag:   row = quad*4 + reg, col = lane&15
// Batched over blockIdx.z = b*16+h with independent b/h strides (elements).
// Requires: gridDim.x*64 == M, gridDim.y*64 == N, K % 32 == 0, 16B alignment.
// ---------------------------------------------------------------------------
template <typename CT>
__global__ __launch_bounds__(256) void gemm_abt(
    const unsigned short* __restrict__ A, const unsigned short* __restrict__ B,
    CT* __restrict__ C,
    int K, int lda, int ldb, int ldc,
    long sAb, long sAh, long sBb, long sBh, long sCb, long sCh)
{
    const int z = blockIdx.z, b = z >> 4, h = z & 15;
    A += (long)b * sAb + (long)h * sAh;
    B += (long)b * sBb + (long)h * sBh;
    C += (long)b * sCb + (long)h * sCh;
    const int lane = threadIdx.x & 63, wave = threadIdx.x >> 6;
    const int m0 = blockIdx.x * 64 + wave * 16;
    const int n0 = blockIdx.y * 64;
    const int l15 = lane & 15, q4 = lane >> 4;
    const unsigned short* Ap = A + (long)(m0 + l15) * lda + q4 * 8;
    const unsigned short* Bp = B + (long)(n0 + l15) * ldb + q4 * 8;
    f32x4 acc0 = {0.f, 0.f, 0.f, 0.f};
    f32x4 acc1 = acc0, acc2 = acc0, acc3 = acc0;
    for (int k0 = 0; k0 < K; k0 += 32) {
        s16x8 af = *(const s16x8*)(Ap + k0);
        s16x8 b0 = *(const s16x8*)(Bp + k0);
        s16x8 b1 = *(const s16x8*)(Bp + 16 * ldb + k0);
        s16x8 b2 = *(const s16x8*)(Bp + 32 * ldb + k0);
        s16x8 b3 = *(const s16x8*)(Bp + 48 * ldb + k0);
        acc0 = __builtin_amdgcn_mfma_f32_16x16x32_bf16(af, b0, acc0, 0, 0, 0);
        acc1 = __builtin_amdgcn_mfma_f32_16x16x32_bf16(af, b1, acc1, 0, 0, 0);
        acc2 = __builtin_amdgcn_mfma_f32_16x16x32_bf16(af, b2, acc2, 0, 0, 0);
        acc3 = __builtin_amdgcn_mfma_f32_16x16x32_bf16(af, b3, acc3, 0, 0, 0);
    }
    const int row0 = m0 + q4 * 4;
    long cb = (long)row0 * ldc + n0 + l15;
#pragma unroll
    for (int r = 0; r < 4; ++r) {
        cstore(&C[cb + (long)r * ldc +  0], acc0[r]);
        cstore(&C[cb + (long)r * ldc + 16], acc1[r]);
        cstore(&C[cb + (long)r * ldc + 32], acc2[r]);
        cstore(&C[cb + (long)r * ldc + 48], acc3[r]);
    }
}

// ---------------------------------------------------------------------------
// In-place RMSNorm over rows of 1536, one block per row.
// ref: ql = w * (ql * rsqrt(mean(ql^2) + 1e-6))
// ---------------------------------------------------------------------------
__global__ __launch_bounds__(256) void rmsnorm_k(unsigned short* __restrict__ ql,
                                                 const unsigned short* __restrict__ w)
{
    const long base = (long)blockIdx.x * 1536;
    const int tid = threadIdx.x;
    float v[6];
    float ss = 0.f;
#pragma unroll
    for (int i = 0; i < 6; ++i) {
        v[i] = b2f(ql[base + tid + i * 256]);
        ss += v[i] * v[i];
    }
#pragma unroll
    for (int off = 32; off; off >>= 1) ss += __shfl_xor(ss, off, 64);
    __shared__ float red[4];
    if ((tid & 63) == 0) red[tid >> 6] = ss;
    __syncthreads();
    const float tot = red[0] + red[1] + red[2] + red[3];
    const float r = rsqrtf(tot * (1.0f / 1536.0f) + 1e-6f);
#pragma unroll
    for (int i = 0; i < 6; ++i) {
        const int idx = tid + i * 256;
        ql[base + idx] = f2b(v[i] * r * b2f(w[idx]));
    }
}

// ---------------------------------------------------------------------------
// RoPE for q (per head) and k. Stays in the reference's permuted layout
// (consistent for q and k -> dot products unchanged).
//   out[j]    = x[2j]*cos_j - x[2j+1]*sin_j
//   out[32+j] = x[2j+1]*cos_j + x[2j]*sin_j ,  j<32, angle=pos*theta^-(j/32)
// block = 512 threads (16 heads x 32 j), grid = B*S.
// q_rope out: (B,NH,S,64); krope out: (B,S,64)
// ---------------------------------------------------------------------------
__global__ __launch_bounds__(512) void rope_k(
    const unsigned short* __restrict__ q, const unsigned short* __restrict__ ckv,
    const int* __restrict__ pos_ids,
    unsigned short* __restrict__ q_rope, unsigned short* __restrict__ krope)
{
    const int bs = blockIdx.x;
    const int b = bs >> 11, s = bs & 2047;
    const int t = threadIdx.x;
    const int j = t & 31, h = t >> 5;
    const float pos = (float)pos_ids[bs];
    const float invf = __expf(-(float)j * 0.4317347f);  // ln(1e6)/32
    float sn, cs;
    sincosf(pos * invf, &sn, &cs);
    const unsigned short* x = q + (long)bs * 3072 + h * 192 + 128;
    const float x0 = b2f(x[2 * j]), x1 = b2f(x[2 * j + 1]);
    const long ob = ((long)(b * NH_N + h) * S_LEN + s) * 64;
    q_rope[ob + j]      = f2b(x0 * cs - x1 * sn);
    q_rope[ob + 32 + j] = f2b(x1 * cs + x0 * sn);
    if (h == 0) {
        const unsigned short* y = ckv + (long)bs * 576 + 512;
        const float y0 = b2f(y[2 * j]), y1 = b2f(y[2 * j + 1]);
        const long ob2 = (long)bs * 64;
        krope[ob2 + j]      = f2b(y0 * cs - y1 * sn);
        krope[ob2 + 32 + j] = f2b(y1 * cs + y0 * sn);
    }
}

// qT[h][c][n] = Wkv_up[(h*256+n)*512 + c]  (so q_abs GEMM is A@B^T form)
__global__ __launch_bounds__(256) void transpose_qabsorb(
    const unsigned short* __restrict__ Wkv_up, unsigned short* __restrict__ qT)
{
    const int idx = blockIdx.x * 256 + threadIdx.x;  // < 16*512*128
    const int n = idx & 127;
    const int c = (idx >> 7) & 511;
    const int h = idx >> 16;
    qT[idx] = Wkv_up[((long)(h * 256 + n)) * 512 + c];
}

// ---------------------------------------------------------------------------
// Flash-style causal attention in the 512-dim latent space.
// One wave per query row; lane owns c-dims [lane*8, lane*8+8) and rope dim lane.
// scores = (q_rope . k_rope + q_abs . ckv) / sqrt(192), online softmax,
// O = softmax(S) @ ckv  -> attn_out (B,NH,S,512).
// ckv is read directly from the raw (B,S,576) buffer (ld = 576).
// ---------------------------------------------------------------------------
__global__ __launch_bounds__(256) void flash_attn(
    const unsigned short* __restrict__ q_rope, const unsigned short* __restrict__ krope,
    const unsigned short* __restrict__ q_abs,  const unsigned short* __restrict__ ckv,
    unsigned short* __restrict__ attn_out)
{
    const float scale = 0.07216878364870323f;  // 1/sqrt(192)
    const int lane = threadIdx.x & 63;
    const int wave = threadIdx.x >> 6;
    const int bh = blockIdx.x;            // b*16+h
    const int b = bh >> 4;
    const int qi = blockIdx.y * 4 + wave;
    const long qoff = (long)bh * S_LEN + qi;

    float qc[8];
    {
        u16x8 v = *(const u16x8*)(q_abs + qoff * 512 + lane * 8);
#pragma unroll
        for (int j = 0; j < 8; ++j) qc[j] = b2f(v[j]);
    }
    const float qr = b2f(q_rope[qoff * 64 + lane]);

    const unsigned short* kc_ptr = ckv + (long)b * S_LEN * 576 + lane * 8;
    const unsigned short* kr_ptr = krope + (long)b * S_LEN * 64 + lane;

    float m = -INFINITY, l = 0.f;
    float o[8] = {0.f, 0.f, 0.f, 0.f, 0.f, 0.f, 0.f, 0.f};

    for (int k = 0; k <= qi; ++k) {
        u16x8 kcv = *(const u16x8*)(kc_ptr + (long)k * 576);
        const float kr = b2f(kr_ptr[(long)k * 64]);
        float part = qr * kr;
        float vc[8];
#pragma unroll
        for (int j = 0; j < 8; ++j) { vc[j] = b2f(kcv[j]); part += qc[j] * vc[j]; }
#pragma unroll
        for (int off = 32; off; off >>= 1) part += __shfl_xor(part, off, 64);
        const float s = part * scale;
        const float mn = fmaxf(m, s);
        const float alpha = __expf(m - mn);   // first iter: exp(-inf)=0
        const float p = __expf(s - mn);
        l = l * alpha + p;
#pragma unroll
        for (int j = 0; j < 8; ++j) o[j] = o[j] * alpha + p * vc[j];
        m = mn;
    }
    const float inv = 1.0f / l;
    u16x8 ov;
#pragma unroll
    for (int j = 0; j < 8; ++j) ov[j] = f2b(o[j] * inv);
    *(u16x8*)(attn_out + qoff * 512 + lane * 8) = ov;
}

// ---------------------------------------------------------------------------
extern "C" void kernel_launch(void* const* d_in, const int* in_sizes, int n_in,
                              void* d_out, int out_size, void* d_ws, size_t ws_size,
                              hipStream_t stream)
{
    (void)in_sizes; (void)n_in; (void)out_size; (void)ws_size;
    const float* hs_f       = (const float*)d_in[0];
    const int*   pos        = (const int*)d_in[1];
    // d_in[2] = attention_mask (causal, recomputed analytically) - unused
    const float* Wq_down_f  = (const float*)d_in[3];
    const float* q_ln_w_f   = (const float*)d_in[4];
    const float* Wq_up_f    = (const float*)d_in[5];
    const float* Wkv_down_f = (const float*)d_in[6];
    const float* Wkv_up_f   = (const float*)d_in[7];
    const float* Wo_f       = (const float*)d_in[8];
    float* out = (float*)d_out;

    // workspace layout (bf16 elements). out2 aliases q (dead after step 7).
    unsigned short* ws    = (unsigned short*)d_ws;
    unsigned short* ql    = ws;                        // 4096*1536
    unsigned short* q     = ql    + 4096L * 1536;      // 4096*3072
    unsigned short* out2  = q;                         // 4096*2048 (alias, step 9+)
    unsigned short* ckv   = q     + 4096L * 3072;      // 4096*576
    unsigned short* krope = ckv   + 4096L * 576;       // 4096*64
    unsigned short* qrope = krope + 4096L * 64;        // 32*2048*64
    unsigned short* qabsT = qrope + 32L * 2048 * 64;   // 16*512*128
    unsigned short* qabs  = qabsT + 16L * 512 * 128;   // 32*2048*512
    unsigned short* attno = qabs  + 32L * 2048 * 512;  // 32*2048*512
    // bf16 copies of fp32 inputs
    unsigned short* hs    = attno + 32L * 2048 * 512;  // 4096*2048
    unsigned short* Wqd   = hs    + 4096L * 2048;      // 1536*2048
    unsigned short* qlnw  = Wqd   + 1536L * 2048;      // 1536
    unsigned short* Wqu   = qlnw  + 1536;              // 3072*1536
    unsigned short* Wkvd  = Wqu   + 3072L * 1536;      // 576*2048
    unsigned short* Wkvu  = Wkvd  + 576L * 2048;       // 16*256*512
    unsigned short* Wob   = Wkvu  + 16L * 256 * 512;   // 2048*2048

    // 0) fp32 -> bf16 input conversion
    f32_to_bf16<<<4096, 256, 0, stream>>>(hs_f,       hs,   4096L * 2048);
    f32_to_bf16<<<3072, 256, 0, stream>>>(Wq_down_f,  Wqd,  1536L * 2048);
    f32_to_bf16<<<2,    256, 0, stream>>>(q_ln_w_f,   qlnw, 1536L);
    f32_to_bf16<<<4096, 256, 0, stream>>>(Wq_up_f,    Wqu,  3072L * 1536);
    f32_to_bf16<<<1152, 256, 0, stream>>>(Wkv_down_f, Wkvd, 576L * 2048);
    f32_to_bf16<<<2048, 256, 0, stream>>>(Wkv_up_f,   Wkvu, 16L * 256 * 512);
    f32_to_bf16<<<4096, 256, 0, stream>>>(Wo_f,       Wob,  2048L * 2048);

    // 1) ql = hs @ Wq_down^T   (4096x1536, K=2048)
    gemm_abt<unsigned short><<<dim3(64, 24, 1), 256, 0, stream>>>(hs, Wqd, ql,
        2048, 2048, 2048, 1536, 0, 0, 0, 0, 0, 0);
    // 2) RMSNorm(ql) in place
    rmsnorm_k<<<4096, 256, 0, stream>>>(ql, qlnw);
    // 3) q = ql @ Wq_up^T      (4096x3072, K=1536)
    gemm_abt<unsigned short><<<dim3(64, 48, 1), 256, 0, stream>>>(ql, Wqu, q,
        1536, 1536, 1536, 3072, 0, 0, 0, 0, 0, 0);
    // 4) ckv = hs @ Wkv_down^T (4096x576, K=2048)
    gemm_abt<unsigned short><<<dim3(64, 9, 1), 256, 0, stream>>>(hs, Wkvd, ckv,
        2048, 2048, 2048, 576, 0, 0, 0, 0, 0, 0);
    // 5) RoPE on q (per head) and k
    rope_k<<<4096, 512, 0, stream>>>(q, ckv, pos, qrope, krope);
    // 6) transpose q_absorb -> (h, c, n)
    transpose_qabsorb<<<4096, 256, 0, stream>>>(Wkvu, qabsT);
    // 7) q_abs[b,h] = q_nope[b,h] @ q_absorbT[h]^T  (2048x512, K=128), batched 32
    gemm_abt<unsigned short><<<dim3(32, 8, 32), 256, 0, stream>>>(q, qabsT, qabs,
        128, 3072, 128, 512,
        2048L * 3072, 192, 0, 512L * 128, 16L * 2048 * 512, 2048L * 512);
    // 8) flash attention -> attn_out (B,NH,S,512)
    flash_attn<<<dim3(32, 512, 1), 256, 0, stream>>>(qrope, krope, qabs, ckv, attno);
    // 9) out2[b,s,h*128+v] = attn_out[b,h,s] . out_absorb[h,v]  (2048x128, K=512), batched 32
    //    (out2 aliases q, which is dead after step 7)
    gemm_abt<unsigned short><<<dim3(32, 2, 32), 256, 0, stream>>>(attno, Wkvu + 128L * 512, out2,
        512, 512, 512, 2048,
        16L * 2048 * 512, 2048L * 512, 0, 256L * 512, 2048L * 2048, 128);
    // 10) out = out2 @ Wo^T    (4096x2048, K=2048), fp32 output
    gemm_abt<float><<<dim3(64, 32, 1), 256, 0, stream>>>(out2, Wob, out,
        2048, 2048, 2048, 2048, 0, 0, 0, 0, 0, 0);
}

// Round 3
// 2644.330 us; speedup vs baseline: 2.7550x; 2.7550x over previous
//
#include <hip/hip_runtime.h>
#include <cstdint>

// Problem constants (MicroCortexMLA): B=2, S=2048, H=2048, NH=16,
// NOPE=128, ROPE=64, VD=128, QLORA=1536, KVLORA=512, theta=1e6, eps=1e-6
// Harness dtypes: fp32 inputs (converted to bf16 in ws), int32 pos, fp32 out.
#define S_LEN 2048
#define NH_N  16

typedef short s16x8 __attribute__((ext_vector_type(8)));
typedef unsigned short u16x8 __attribute__((ext_vector_type(8)));
typedef float f32x4 __attribute__((ext_vector_type(4)));

__device__ __forceinline__ float b2f(unsigned short u) {
    return __uint_as_float(((uint32_t)u) << 16);
}
// round-to-nearest-even f32 -> bf16
__device__ __forceinline__ unsigned short f2b(float f) {
    uint32_t x = __float_as_uint(f);
    x += 0x7fffu + ((x >> 16) & 1u);
    return (unsigned short)(x >> 16);
}

__device__ __forceinline__ void cstore(unsigned short* p, float v) { *p = f2b(v); }
__device__ __forceinline__ void cstore(float* p, float v) { *p = v; }

// ---------------------------------------------------------------------------
// fp32 -> bf16 conversion, vectorized x4, grid-stride. n % 4 == 0.
// ---------------------------------------------------------------------------
__global__ __launch_bounds__(256) void f32_to_bf16(const float* __restrict__ in,
                                                   unsigned short* __restrict__ out,
                                                   long n)
{
    const long nv = n >> 2;
    long i = (long)blockIdx.x * blockDim.x + threadIdx.x;
    const long stride = (long)gridDim.x * blockDim.x;
    for (; i < nv; i += stride) {
        float4 v = ((const float4*)in)[i];
        ushort4 o;
        o.x = f2b(v.x); o.y = f2b(v.y); o.z = f2b(v.z); o.w = f2b(v.w);
        ((ushort4*)out)[i] = o;
    }
}

// ---------------------------------------------------------------------------
// C = A @ B^T   (A: MxK row-major, B: NxK row-major, C: MxN row-major)
// A,B bf16; C bf16 or fp32. block = 256 = 4 waves; block tile 64x64;
// wave computes 16(m) x 64(n) via mfma_f32_16x16x32_bf16.
// Fragment layouts (HW-verified on gfx950):
//   A/B frag: elem (lane&15, quad*8+j)  -> one 16B contiguous load per frag
//   D frag:   row = quad*4 + reg, col = lane&15
// ---------------------------------------------------------------------------
template <typename CT>
__global__ __launch_bounds__(256) void gemm_abt(
    const unsigned short* __restrict__ A, const unsigned short* __restrict__ B,
    CT* __restrict__ C,
    int K, int lda, int ldb, int ldc,
    long sAb, long sAh, long sBb, long sBh, long sCb, long sCh)
{
    const int z = blockIdx.z, b = z >> 4, h = z & 15;
    A += (long)b * sAb + (long)h * sAh;
    B += (long)b * sBb + (long)h * sBh;
    C += (long)b * sCb + (long)h * sCh;
    const int lane = threadIdx.x & 63, wave = threadIdx.x >> 6;
    const int m0 = blockIdx.x * 64 + wave * 16;
    const int n0 = blockIdx.y * 64;
    const int l15 = lane & 15, q4 = lane >> 4;
    const unsigned short* Ap = A + (long)(m0 + l15) * lda + q4 * 8;
    const unsigned short* Bp = B + (long)(n0 + l15) * ldb + q4 * 8;
    f32x4 acc0 = {0.f, 0.f, 0.f, 0.f};
    f32x4 acc1 = acc0, acc2 = acc0, acc3 = acc0;
    for (int k0 = 0; k0 < K; k0 += 32) {
        s16x8 af = *(const s16x8*)(Ap + k0);
        s16x8 b0 = *(const s16x8*)(Bp + k0);
        s16x8 b1 = *(const s16x8*)(Bp + 16 * ldb + k0);
        s16x8 b2 = *(const s16x8*)(Bp + 32 * ldb + k0);
        s16x8 b3 = *(const s16x8*)(Bp + 48 * ldb + k0);
        acc0 = __builtin_amdgcn_mfma_f32_16x16x32_bf16(af, b0, acc0, 0, 0, 0);
        acc1 = __builtin_amdgcn_mfma_f32_16x16x32_bf16(af, b1, acc1, 0, 0, 0);
        acc2 = __builtin_amdgcn_mfma_f32_16x16x32_bf16(af, b2, acc2, 0, 0, 0);
        acc3 = __builtin_amdgcn_mfma_f32_16x16x32_bf16(af, b3, acc3, 0, 0, 0);
    }
    const int row0 = m0 + q4 * 4;
    long cb = (long)row0 * ldc + n0 + l15;
#pragma unroll
    for (int r = 0; r < 4; ++r) {
        cstore(&C[cb + (long)r * ldc +  0], acc0[r]);
        cstore(&C[cb + (long)r * ldc + 16], acc1[r]);
        cstore(&C[cb + (long)r * ldc + 32], acc2[r]);
        cstore(&C[cb + (long)r * ldc + 48], acc3[r]);
    }
}

// ---------------------------------------------------------------------------
// In-place RMSNorm over rows of 1536, one block per row.
// ---------------------------------------------------------------------------
__global__ __launch_bounds__(256) void rmsnorm_k(unsigned short* __restrict__ ql,
                                                 const unsigned short* __restrict__ w)
{
    const long base = (long)blockIdx.x * 1536;
    const int tid = threadIdx.x;
    float v[6];
    float ss = 0.f;
#pragma unroll
    for (int i = 0; i < 6; ++i) {
        v[i] = b2f(ql[base + tid + i * 256]);
        ss += v[i] * v[i];
    }
#pragma unroll
    for (int off = 32; off; off >>= 1) ss += __shfl_xor(ss, off, 64);
    __shared__ float red[4];
    if ((tid & 63) == 0) red[tid >> 6] = ss;
    __syncthreads();
    const float tot = red[0] + red[1] + red[2] + red[3];
    const float r = rsqrtf(tot * (1.0f / 1536.0f) + 1e-6f);
#pragma unroll
    for (int i = 0; i < 6; ++i) {
        const int idx = tid + i * 256;
        ql[base + idx] = f2b(v[i] * r * b2f(w[idx]));
    }
}

// ---------------------------------------------------------------------------
// RoPE for q (per head) and k (reference's permuted layout, consistent q/k).
// ---------------------------------------------------------------------------
__global__ __launch_bounds__(512) void rope_k(
    const unsigned short* __restrict__ q, const unsigned short* __restrict__ ckv,
    const int* __restrict__ pos_ids,
    unsigned short* __restrict__ q_rope, unsigned short* __restrict__ krope)
{
    const int bs = blockIdx.x;
    const int b = bs >> 11, s = bs & 2047;
    const int t = threadIdx.x;
    const int j = t & 31, h = t >> 5;
    const float pos = (float)pos_ids[bs];
    const float invf = __expf(-(float)j * 0.4317347f);  // ln(1e6)/32
    float sn, cs;
    sincosf(pos * invf, &sn, &cs);
    const unsigned short* x = q + (long)bs * 3072 + h * 192 + 128;
    const float x0 = b2f(x[2 * j]), x1 = b2f(x[2 * j + 1]);
    const long ob = ((long)(b * NH_N + h) * S_LEN + s) * 64;
    q_rope[ob + j]      = f2b(x0 * cs - x1 * sn);
    q_rope[ob + 32 + j] = f2b(x1 * cs + x0 * sn);
    if (h == 0) {
        const unsigned short* y = ckv + (long)bs * 576 + 512;
        const float y0 = b2f(y[2 * j]), y1 = b2f(y[2 * j + 1]);
        const long ob2 = (long)bs * 64;
        krope[ob2 + j]      = f2b(y0 * cs - y1 * sn);
        krope[ob2 + 32 + j] = f2b(y1 * cs + y0 * sn);
    }
}

// qT[h][c][n] = Wkv_up[(h*256+n)*512 + c]
__global__ __launch_bounds__(256) void transpose_qabsorb(
    const unsigned short* __restrict__ Wkv_up, unsigned short* __restrict__ qT)
{
    const int idx = blockIdx.x * 256 + threadIdx.x;
    const int n = idx & 127;
    const int c = (idx >> 7) & 511;
    const int h = idx >> 16;
    qT[idx] = Wkv_up[((long)(h * 256 + n)) * 512 + c];
}

// ---------------------------------------------------------------------------
// VT_g[b][c][key] = ckv[b][key][c]  (c < 512) — V^T for the PV MFMA B-frags.
// Tiled 64x64 transpose through LDS. grid (32 keyblk, 8 cblk, 2 b).
// ---------------------------------------------------------------------------
__global__ __launch_bounds__(256) void transpose_ckv(
    const unsigned short* __restrict__ ckv, unsigned short* __restrict__ VT_g)
{
    __shared__ unsigned short t[64][72];  // +8 pad
    const int k0 = blockIdx.x * 64, c0 = blockIdx.y * 64, b = blockIdx.z;
    const int tid = threadIdx.x;
#pragma unroll
    for (int it = 0; it < 2; ++it) {
        int idx = tid + it * 256;  // 512 tasks: 64 rows x 8 granules
        int row = idx >> 3, g = idx & 7;
        *(s16x8*)&t[row][g * 8] =
            *(const s16x8*)(ckv + ((long)(b * S_LEN + k0 + row) * 576 + c0 + g * 8));
    }
    __syncthreads();
#pragma unroll
    for (int it = 0; it < 2; ++it) {
        int idx = tid + it * 256;  // 512 tasks: 64 c x 8 key-granules
        int c = idx >> 3, g = idx & 7;
        u16x8 v;
#pragma unroll
        for (int j = 0; j < 8; ++j) v[j] = t[g * 8 + j][c];
        *(u16x8*)(VT_g + ((long)(b * 512 + c0 + c) * S_LEN + k0 + g * 8)) = v;
    }
}

// ---------------------------------------------------------------------------
// MFMA flash attention in the 576-dim latent space (512 c + 64 rope).
// grid (32 qtiles, 32 bh), block 256 (4 waves). Per wg: 64 q-rows.
// S-phase: wave w computes rows w*16..+16 x 32-key tile; Q-frags (18) resident
//   in regs; K-tile in LDS (rows padded +8 elems for bank spread).
// Online softmax in D-layout (row=quad*4+reg), P round-trips through LDS.
// PV-phase: wave w computes ALL 64 rows x c-chunk [w*128,(w+1)*128):
//   A=P frags (4 mb), B=VT frags (8 nb) from swizzled LDS; O acc = 128 regs.
// ---------------------------------------------------------------------------
__global__ __launch_bounds__(256, 2) void flash_mfma(
    const unsigned short* __restrict__ qabs,  const unsigned short* __restrict__ qrope,
    const unsigned short* __restrict__ ckv,   const unsigned short* __restrict__ krope,
    const unsigned short* __restrict__ VT_g,  unsigned short* __restrict__ attn_out)
{
    __shared__ unsigned short K_lds[32 * 584];   // 32 keys x (576 + 8 pad)
    __shared__ unsigned short VT_lds[512 * 32];  // XOR-swizzled granules
    __shared__ unsigned short P_lds[64 * 40];    // 64 rows x (32 + 8 pad)
    __shared__ float af_lds[64];                 // alpha per row; reused for l

    const float scale = 0.07216878364870323f;  // 1/sqrt(192)
    const int tid = threadIdx.x;
    const int lane = tid & 63, w = tid >> 6;
    const int l15 = lane & 15, q4 = lane >> 4;
    const int qt = 31 - blockIdx.x;           // long tiles first
    const int bh = blockIdx.y;
    const int b = bh >> 4;
    const int q0 = qt * 64;

    // Q fragments: rows q0 + w*16 + l15, dims kb*32 + q4*8 (+j)
    s16x8 qf[18];
    {
        const unsigned short* qa = qabs + ((long)bh * S_LEN + q0 + w * 16 + l15) * 512 + q4 * 8;
#pragma unroll
        for (int kb = 0; kb < 16; ++kb) qf[kb] = *(const s16x8*)(qa + kb * 32);
        const unsigned short* qr = qrope + ((long)bh * S_LEN + q0 + w * 16 + l15) * 64 + q4 * 8;
        qf[16] = *(const s16x8*)(qr);
        qf[17] = *(const s16x8*)(qr + 32);
    }

    f32x4 O[4][8];
#pragma unroll
    for (int mb = 0; mb < 4; ++mb)
#pragma unroll
        for (int nb = 0; nb < 8; ++nb) O[mb][nb] = (f32x4){0.f, 0.f, 0.f, 0.f};
    float m_i[4] = {-INFINITY, -INFINITY, -INFINITY, -INFINITY};
    float l_i[4] = {0.f, 0.f, 0.f, 0.f};

    const int nkt = 2 * qt + 2;
    for (int kt = 0; kt < nkt; ++kt) {
        const int k0 = kt * 32;
        // ---- stage K-tile (32 x 576) + VT-tile (512 x 32) ----
#pragma unroll
        for (int it = 0; it < 9; ++it) {
            int idx = tid + it * 256;          // 2304 granules
            int key = idx / 72, g = idx - key * 72;
            const unsigned short* src = (g < 64)
                ? ckv  + ((long)(b * S_LEN + k0 + key) * 576 + g * 8)
                : krope + ((long)(b * S_LEN + k0 + key) * 64 + (g - 64) * 8);
            *(s16x8*)(&K_lds[key * 584 + g * 8]) = *(const s16x8*)src;
        }
#pragma unroll
        for (int it = 0; it < 8; ++it) {
            int idx = tid + it * 256;          // 2048 granules
            int c = idx >> 2, g = idx & 3;
            int gs = g ^ ((c >> 1) & 3);
            *(s16x8*)(&VT_lds[c * 32 + gs * 8]) =
                *(const s16x8*)(VT_g + ((long)(b * 512 + c) * S_LEN + k0 + g * 8));
        }
        __syncthreads();

        // ---- S-phase: rows w*16..+16 x 32 keys ----
        f32x4 s0 = {0.f, 0.f, 0.f, 0.f}, s1 = s0;
        {
            const unsigned short* kb0 = &K_lds[(l15)*584 + q4 * 8];
            const unsigned short* kb1 = &K_lds[(16 + l15) * 584 + q4 * 8];
#pragma unroll
            for (int kb = 0; kb < 18; ++kb) {
                s16x8 k0f = *(const s16x8*)(kb0 + kb * 32);
                s16x8 k1f = *(const s16x8*)(kb1 + kb * 32);
                s0 = __builtin_amdgcn_mfma_f32_16x16x32_bf16(qf[kb], k0f, s0, 0, 0, 0);
                s1 = __builtin_amdgcn_mfma_f32_16x16x32_bf16(qf[kb], k1f, s1, 0, 0, 0);
            }
        }
#pragma unroll
        for (int r = 0; r < 4; ++r) { s0[r] *= scale; s1[r] *= scale; }
        if (kt >= 2 * qt) {  // diagonal tiles: causal mask
#pragma unroll
            for (int r = 0; r < 4; ++r) {
                int qg = q0 + w * 16 + q4 * 4 + r;
                if (k0 + l15 > qg)      s0[r] = -INFINITY;
                if (k0 + 16 + l15 > qg) s1[r] = -INFINITY;
            }
        }
        // online softmax + P write
#pragma unroll
        for (int r = 0; r < 4; ++r) {
            float mx = fmaxf(s0[r], s1[r]);
#pragma unroll
            for (int off = 1; off < 16; off <<= 1) mx = fmaxf(mx, __shfl_xor(mx, off, 64));
            const float mn = fmaxf(m_i[r], mx);
            const float al = __expf(m_i[r] - mn);   // first iter: exp(-inf)=0
            m_i[r] = mn;
            const float p0 = __expf(s0[r] - mn);
            const float p1 = __expf(s1[r] - mn);
            float ps = p0 + p1;
#pragma unroll
            for (int off = 1; off < 16; off <<= 1) ps += __shfl_xor(ps, off, 64);
            l_i[r] = l_i[r] * al + ps;
            const int row = w * 16 + q4 * 4 + r;
            P_lds[row * 40 + l15]      = f2b(p0);
            P_lds[row * 40 + 16 + l15] = f2b(p1);
            if (l15 == 0) af_lds[row] = al;
        }
        __syncthreads();

        // ---- PV-phase: all 64 rows x c-chunk [w*128, (w+1)*128) ----
        // rescale O by alpha[row]
#pragma unroll
        for (int mb = 0; mb < 4; ++mb) {
#pragma unroll
            for (int r = 0; r < 4; ++r) {
                const float al = af_lds[mb * 16 + q4 * 4 + r];
#pragma unroll
                for (int nb = 0; nb < 8; ++nb) O[mb][nb][r] *= al;
            }
        }
        s16x8 pf[4];
#pragma unroll
        for (int mb = 0; mb < 4; ++mb)
            pf[mb] = *(const s16x8*)&P_lds[(mb * 16 + l15) * 40 + q4 * 8];
#pragma unroll
        for (int nb = 0; nb < 8; ++nb) {
            const int c = w * 128 + nb * 16 + l15;
            const int gs = q4 ^ ((c >> 1) & 3);
            s16x8 vf = *(const s16x8*)&VT_lds[c * 32 + gs * 8];
#pragma unroll
            for (int mb = 0; mb < 4; ++mb)
                O[mb][nb] = __builtin_amdgcn_mfma_f32_16x16x32_bf16(pf[mb], vf, O[mb][nb], 0, 0, 0);
        }
        __syncthreads();
    }

    // epilogue: O /= l, store bf16
#pragma unroll
    for (int r = 0; r < 4; ++r)
        if (l15 == 0) af_lds[w * 16 + q4 * 4 + r] = l_i[r];
    __syncthreads();
#pragma unroll
    for (int mb = 0; mb < 4; ++mb) {
#pragma unroll
        for (int r = 0; r < 4; ++r) {
            const float inv = 1.0f / af_lds[mb * 16 + q4 * 4 + r];
            const long rowbase = ((long)bh * S_LEN + q0 + mb * 16 + q4 * 4 + r) * 512;
#pragma unroll
            for (int nb = 0; nb < 8; ++nb)
                attn_out[rowbase + w * 128 + nb * 16 + l15] = f2b(O[mb][nb][r] * inv);
        }
    }
}

// ---------------------------------------------------------------------------
extern "C" void kernel_launch(void* const* d_in, const int* in_sizes, int n_in,
                              void* d_out, int out_size, void* d_ws, size_t ws_size,
                              hipStream_t stream)
{
    (void)in_sizes; (void)n_in; (void)out_size; (void)ws_size;
    const float* hs_f       = (const float*)d_in[0];
    const int*   pos        = (const int*)d_in[1];
    // d_in[2] = attention_mask (causal, recomputed analytically) - unused
    const float* Wq_down_f  = (const float*)d_in[3];
    const float* q_ln_w_f   = (const float*)d_in[4];
    const float* Wq_up_f    = (const float*)d_in[5];
    const float* Wkv_down_f = (const float*)d_in[6];
    const float* Wkv_up_f   = (const float*)d_in[7];
    const float* Wo_f       = (const float*)d_in[8];
    float* out = (float*)d_out;

    // workspace layout (bf16 elements). out2 aliases q (dead after step 7).
    unsigned short* ws    = (unsigned short*)d_ws;
    unsigned short* ql    = ws;                        // 4096*1536
    unsigned short* q     = ql    + 4096L * 1536;      // 4096*3072
    unsigned short* out2  = q;                         // 4096*2048 (alias)
    unsigned short* ckv   = q     + 4096L * 3072;      // 4096*576
    unsigned short* krope = ckv   + 4096L * 576;       // 4096*64
    unsigned short* qrope = krope + 4096L * 64;        // 32*2048*64
    unsigned short* qabsT = qrope + 32L * 2048 * 64;   // 16*512*128
    unsigned short* qabs  = qabsT + 16L * 512 * 128;   // 32*2048*512
    unsigned short* attno = qabs  + 32L * 2048 * 512;  // 32*2048*512
    unsigned short* hs    = attno + 32L * 2048 * 512;  // 4096*2048
    unsigned short* Wqd   = hs    + 4096L * 2048;      // 1536*2048
    unsigned short* qlnw  = Wqd   + 1536L * 2048;      // 1536
    unsigned short* Wqu   = qlnw  + 1536;              // 3072*1536
    unsigned short* Wkvd  = Wqu   + 3072L * 1536;      // 576*2048
    unsigned short* Wkvu  = Wkvd  + 576L * 2048;       // 16*256*512
    unsigned short* Wob   = Wkvu  + 16L * 256 * 512;   // 2048*2048
    unsigned short* VTg   = Wob   + 2048L * 2048;      // 2*512*2048

    // 0) fp32 -> bf16 input conversion
    f32_to_bf16<<<4096, 256, 0, stream>>>(hs_f,       hs,   4096L * 2048);
    f32_to_bf16<<<3072, 256, 0, stream>>>(Wq_down_f,  Wqd,  1536L * 2048);
    f32_to_bf16<<<2,    256, 0, stream>>>(q_ln_w_f,   qlnw, 1536L);
    f32_to_bf16<<<4096, 256, 0, stream>>>(Wq_up_f,    Wqu,  3072L * 1536);
    f32_to_bf16<<<1152, 256, 0, stream>>>(Wkv_down_f, Wkvd, 576L * 2048);
    f32_to_bf16<<<2048, 256, 0, stream>>>(Wkv_up_f,   Wkvu, 16L * 256 * 512);
    f32_to_bf16<<<4096, 256, 0, stream>>>(Wo_f,       Wob,  2048L * 2048);

    // 1) ql = hs @ Wq_down^T   (4096x1536, K=2048)
    gemm_abt<unsigned short><<<dim3(64, 24, 1), 256, 0, stream>>>(hs, Wqd, ql,
        2048, 2048, 2048, 1536, 0, 0, 0, 0, 0, 0);
    // 2) RMSNorm(ql)
    rmsnorm_k<<<4096, 256, 0, stream>>>(ql, qlnw);
    // 3) q = ql @ Wq_up^T      (4096x3072, K=1536)
    gemm_abt<unsigned short><<<dim3(64, 48, 1), 256, 0, stream>>>(ql, Wqu, q,
        1536, 1536, 1536, 3072, 0, 0, 0, 0, 0, 0);
    // 4) ckv = hs @ Wkv_down^T (4096x576, K=2048)
    gemm_abt<unsigned short><<<dim3(64, 9, 1), 256, 0, stream>>>(hs, Wkvd, ckv,
        2048, 2048, 2048, 576, 0, 0, 0, 0, 0, 0);
    // 5) RoPE on q (per head) and k
    rope_k<<<4096, 512, 0, stream>>>(q, ckv, pos, qrope, krope);
    // 5b) VT_g[b][c][key] = ckv[b][key][c]
    transpose_ckv<<<dim3(32, 8, 2), 256, 0, stream>>>(ckv, VTg);
    // 6) transpose q_absorb -> (h, c, n)
    transpose_qabsorb<<<4096, 256, 0, stream>>>(Wkvu, qabsT);
    // 7) q_abs[b,h] = q_nope[b,h] @ q_absorbT[h]^T  (2048x512, K=128), batched 32
    gemm_abt<unsigned short><<<dim3(32, 8, 32), 256, 0, stream>>>(q, qabsT, qabs,
        128, 3072, 128, 512,
        2048L * 3072, 192, 0, 512L * 128, 16L * 2048 * 512, 2048L * 512);
    // 8) MFMA flash attention -> attn_out (B,NH,S,512)
    flash_mfma<<<dim3(32, 32, 1), 256, 0, stream>>>(qabs, qrope, ckv, krope, VTg, attno);
    // 9) out2 = attn_out @ out_absorb^T per head (2048x128, K=512), batched 32
    gemm_abt<unsigned short><<<dim3(32, 2, 32), 256, 0, stream>>>(attno, Wkvu + 128L * 512, out2,
        512, 512, 512, 2048,
        16L * 2048 * 512, 2048L * 512, 0, 256L * 512, 2048L * 2048, 128);
    // 10) out = out2 @ Wo^T    (4096x2048, K=2048), fp32 output
    gemm_abt<float><<<dim3(64, 32, 1), 256, 0, stream>>>(out2, Wob, out,
        2048, 2048, 2048, 2048, 0, 0, 0, 0, 0, 0);
}

// Round 4
// 1969.762 us; speedup vs baseline: 3.6985x; 1.3425x over previous
//
#include <hip/hip_runtime.h>
#include <cstdint>

// Problem constants (MicroCortexMLA): B=2, S=2048, H=2048, NH=16,
// NOPE=128, ROPE=64, VD=128, QLORA=1536, KVLORA=512, theta=1e6, eps=1e-6
// Harness dtypes: fp32 inputs (converted to bf16 in ws), int32 pos, fp32 out.
#define S_LEN 2048
#define NH_N  16

typedef short s16x8 __attribute__((ext_vector_type(8)));
typedef unsigned short u16x8 __attribute__((ext_vector_type(8)));
typedef float f32x4 __attribute__((ext_vector_type(4)));

__device__ __forceinline__ float b2f(unsigned short u) {
    return __uint_as_float(((uint32_t)u) << 16);
}
// round-to-nearest-even f32 -> bf16
__device__ __forceinline__ unsigned short f2b(float f) {
    uint32_t x = __float_as_uint(f);
    x += 0x7fffu + ((x >> 16) & 1u);
    return (unsigned short)(x >> 16);
}

__device__ __forceinline__ void cstore(unsigned short* p, float v) { *p = f2b(v); }
__device__ __forceinline__ void cstore(float* p, float v) { *p = v; }

// async global->LDS DMA, 16B per lane. LDS dst is wave-uniform base; HW adds
// lane*16. Tracked by vmcnt; __syncthreads() drains it.
__device__ __forceinline__ void gl2lds16(const void* g, void* l) {
    __builtin_amdgcn_global_load_lds(
        (const __attribute__((address_space(1))) unsigned int*)g,
        (__attribute__((address_space(3))) unsigned int*)l, 16, 0, 0);
}

// ---------------------------------------------------------------------------
// fp32 -> bf16 conversion, vectorized x4, grid-stride. n % 4 == 0.
// ---------------------------------------------------------------------------
__global__ __launch_bounds__(256) void f32_to_bf16(const float* __restrict__ in,
                                                   unsigned short* __restrict__ out,
                                                   long n)
{
    const long nv = n >> 2;
    long i = (long)blockIdx.x * blockDim.x + threadIdx.x;
    const long stride = (long)gridDim.x * blockDim.x;
    for (; i < nv; i += stride) {
        float4 v = ((const float4*)in)[i];
        ushort4 o;
        o.x = f2b(v.x); o.y = f2b(v.y); o.z = f2b(v.z); o.w = f2b(v.w);
        ((ushort4*)out)[i] = o;
    }
}

// ---------------------------------------------------------------------------
// C = A @ B^T   (A: MxK row-major, B: NxK row-major, C: MxN row-major)
// A,B bf16; C bf16 or fp32. block = 256 = 4 waves; block tile 64x64;
// wave computes 16(m) x 64(n) via mfma_f32_16x16x32_bf16.
// Fragment layouts (HW-verified on gfx950):
//   A/B frag: elem (lane&15, quad*8+j)  -> one 16B contiguous load per frag
//   D frag:   row = quad*4 + reg, col = lane&15
// ---------------------------------------------------------------------------
template <typename CT>
__global__ __launch_bounds__(256) void gemm_abt(
    const unsigned short* __restrict__ A, const unsigned short* __restrict__ B,
    CT* __restrict__ C,
    int K, int lda, int ldb, int ldc,
    long sAb, long sAh, long sBb, long sBh, long sCb, long sCh)
{
    const int z = blockIdx.z, b = z >> 4, h = z & 15;
    A += (long)b * sAb + (long)h * sAh;
    B += (long)b * sBb + (long)h * sBh;
    C += (long)b * sCb + (long)h * sCh;
    const int lane = threadIdx.x & 63, wave = threadIdx.x >> 6;
    const int m0 = blockIdx.x * 64 + wave * 16;
    const int n0 = blockIdx.y * 64;
    const int l15 = lane & 15, q4 = lane >> 4;
    const unsigned short* Ap = A + (long)(m0 + l15) * lda + q4 * 8;
    const unsigned short* Bp = B + (long)(n0 + l15) * ldb + q4 * 8;
    f32x4 acc0 = {0.f, 0.f, 0.f, 0.f};
    f32x4 acc1 = acc0, acc2 = acc0, acc3 = acc0;
    for (int k0 = 0; k0 < K; k0 += 32) {
        s16x8 af = *(const s16x8*)(Ap + k0);
        s16x8 b0 = *(const s16x8*)(Bp + k0);
        s16x8 b1 = *(const s16x8*)(Bp + 16 * ldb + k0);
        s16x8 b2 = *(const s16x8*)(Bp + 32 * ldb + k0);
        s16x8 b3 = *(const s16x8*)(Bp + 48 * ldb + k0);
        acc0 = __builtin_amdgcn_mfma_f32_16x16x32_bf16(af, b0, acc0, 0, 0, 0);
        acc1 = __builtin_amdgcn_mfma_f32_16x16x32_bf16(af, b1, acc1, 0, 0, 0);
        acc2 = __builtin_amdgcn_mfma_f32_16x16x32_bf16(af, b2, acc2, 0, 0, 0);
        acc3 = __builtin_amdgcn_mfma_f32_16x16x32_bf16(af, b3, acc3, 0, 0, 0);
    }
    const int row0 = m0 + q4 * 4;
    long cb = (long)row0 * ldc + n0 + l15;
#pragma unroll
    for (int r = 0; r < 4; ++r) {
        cstore(&C[cb + (long)r * ldc +  0], acc0[r]);
        cstore(&C[cb + (long)r * ldc + 16], acc1[r]);
        cstore(&C[cb + (long)r * ldc + 32], acc2[r]);
        cstore(&C[cb + (long)r * ldc + 48], acc3[r]);
    }
}

// ---------------------------------------------------------------------------
// In-place RMSNorm over rows of 1536, one block per row.
// ---------------------------------------------------------------------------
__global__ __launch_bounds__(256) void rmsnorm_k(unsigned short* __restrict__ ql,
                                                 const unsigned short* __restrict__ w)
{
    const long base = (long)blockIdx.x * 1536;
    const int tid = threadIdx.x;
    float v[6];
    float ss = 0.f;
#pragma unroll
    for (int i = 0; i < 6; ++i) {
        v[i] = b2f(ql[base + tid + i * 256]);
        ss += v[i] * v[i];
    }
#pragma unroll
    for (int off = 32; off; off >>= 1) ss += __shfl_xor(ss, off, 64);
    __shared__ float red[4];
    if ((tid & 63) == 0) red[tid >> 6] = ss;
    __syncthreads();
    const float tot = red[0] + red[1] + red[2] + red[3];
    const float r = rsqrtf(tot * (1.0f / 1536.0f) + 1e-6f);
#pragma unroll
    for (int i = 0; i < 6; ++i) {
        const int idx = tid + i * 256;
        ql[base + idx] = f2b(v[i] * r * b2f(w[idx]));
    }
}

// ---------------------------------------------------------------------------
// RoPE for q (per head) and k (reference's permuted layout, consistent q/k).
// ---------------------------------------------------------------------------
__global__ __launch_bounds__(512) void rope_k(
    const unsigned short* __restrict__ q, const unsigned short* __restrict__ ckv,
    const int* __restrict__ pos_ids,
    unsigned short* __restrict__ q_rope, unsigned short* __restrict__ krope)
{
    const int bs = blockIdx.x;
    const int b = bs >> 11, s = bs & 2047;
    const int t = threadIdx.x;
    const int j = t & 31, h = t >> 5;
    const float pos = (float)pos_ids[bs];
    const float invf = __expf(-(float)j * 0.4317347f);  // ln(1e6)/32
    float sn, cs;
    sincosf(pos * invf, &sn, &cs);
    const unsigned short* x = q + (long)bs * 3072 + h * 192 + 128;
    const float x0 = b2f(x[2 * j]), x1 = b2f(x[2 * j + 1]);
    const long ob = ((long)(b * NH_N + h) * S_LEN + s) * 64;
    q_rope[ob + j]      = f2b(x0 * cs - x1 * sn);
    q_rope[ob + 32 + j] = f2b(x1 * cs + x0 * sn);
    if (h == 0) {
        const unsigned short* y = ckv + (long)bs * 576 + 512;
        const float y0 = b2f(y[2 * j]), y1 = b2f(y[2 * j + 1]);
        const long ob2 = (long)bs * 64;
        krope[ob2 + j]      = f2b(y0 * cs - y1 * sn);
        krope[ob2 + 32 + j] = f2b(y1 * cs + y0 * sn);
    }
}

// qT[h][c][n] = Wkv_up[(h*256+n)*512 + c]
__global__ __launch_bounds__(256) void transpose_qabsorb(
    const unsigned short* __restrict__ Wkv_up, unsigned short* __restrict__ qT)
{
    const int idx = blockIdx.x * 256 + threadIdx.x;
    const int n = idx & 127;
    const int c = (idx >> 7) & 511;
    const int h = idx >> 16;
    qT[idx] = Wkv_up[((long)(h * 256 + n)) * 512 + c];
}

// ---------------------------------------------------------------------------
// VT_g[b][c][key] = ckv[b][key][c]  (c < 512) — V^T for the PV MFMA B-frags.
// Tiled 64x64 transpose through LDS. grid (32 keyblk, 8 cblk, 2 b).
// ---------------------------------------------------------------------------
__global__ __launch_bounds__(256) void transpose_ckv(
    const unsigned short* __restrict__ ckv, unsigned short* __restrict__ VT_g)
{
    __shared__ unsigned short t[64][72];  // +8 pad
    const int k0 = blockIdx.x * 64, c0 = blockIdx.y * 64, b = blockIdx.z;
    const int tid = threadIdx.x;
#pragma unroll
    for (int it = 0; it < 2; ++it) {
        int idx = tid + it * 256;  // 512 tasks: 64 rows x 8 granules
        int row = idx >> 3, g = idx & 7;
        *(s16x8*)&t[row][g * 8] =
            *(const s16x8*)(ckv + ((long)(b * S_LEN + k0 + row) * 576 + c0 + g * 8));
    }
    __syncthreads();
#pragma unroll
    for (int it = 0; it < 2; ++it) {
        int idx = tid + it * 256;  // 512 tasks: 64 c x 8 key-granules
        int c = idx >> 3, g = idx & 7;
        u16x8 v;
#pragma unroll
        for (int j = 0; j < 8; ++j) v[j] = t[g * 8 + j][c];
        *(u16x8*)(VT_g + ((long)(b * 512 + c0 + c) * S_LEN + k0 + g * 8)) = v;
    }
}

// ---------------------------------------------------------------------------
// MFMA flash attention in the 576-dim latent space (512 c + 64 rope).
// grid (32 bh, 32 y), qt = 31-y (long blocks dispatch first). block 256.
// Staging via global_load_lds DMA (16B/lane, all 17 issues in flight/thread):
//   K_lds:  32 keys x 576 (unpadded); LDS granule p of row `key` holds logical
//           granule u = (p&~7)|((p&7)^(key&7))  -> S-frag reads 2-way max.
//   VT_lds: [c][4 granules]; position g holds logical granule g^((c>>1)&3).
// S-phase: wave w: rows w*16..+16 x 32 keys, Q-frags (18) resident in regs.
// Online softmax in D-layout (row=quad*4+reg); P via LDS round-trip.
// PV-phase: wave w: ALL 64 rows x c-chunk [w*128,(w+1)*128); O = 128 acc.
// ---------------------------------------------------------------------------
__global__ __launch_bounds__(256, 2) void flash_mfma(
    const unsigned short* __restrict__ qabs,  const unsigned short* __restrict__ qrope,
    const unsigned short* __restrict__ ckv,   const unsigned short* __restrict__ krope,
    const unsigned short* __restrict__ VT_g,  unsigned short* __restrict__ attn_out)
{
    __shared__ unsigned short K_lds[32 * 576];   // source-swizzled granules
    __shared__ unsigned short VT_lds[512 * 32];  // source-swizzled granules
    __shared__ unsigned short P_lds[64 * 40];    // 64 rows x (32 + 8 pad)
    __shared__ float af_lds[64];                 // alpha per row; reused for l

    const float scale = 0.07216878364870323f;  // 1/sqrt(192)
    const int tid = threadIdx.x;
    const int lane = tid & 63, w = tid >> 6;
    const int l15 = lane & 15, q4 = lane >> 4;
    const int bh = blockIdx.x;
    const int qt = 31 - blockIdx.y;           // long tiles first
    const int b = bh >> 4;
    const int q0 = qt * 64;

    // Q fragments: rows q0 + w*16 + l15, dims kb*32 + q4*8 (+j)
    s16x8 qf[18];
    {
        const unsigned short* qa = qabs + ((long)bh * S_LEN + q0 + w * 16 + l15) * 512 + q4 * 8;
#pragma unroll
        for (int kb = 0; kb < 16; ++kb) qf[kb] = *(const s16x8*)(qa + kb * 32);
        const unsigned short* qr = qrope + ((long)bh * S_LEN + q0 + w * 16 + l15) * 64 + q4 * 8;
        qf[16] = *(const s16x8*)(qr);
        qf[17] = *(const s16x8*)(qr + 32);
    }

    f32x4 O[4][8];
#pragma unroll
    for (int mb = 0; mb < 4; ++mb)
#pragma unroll
        for (int nb = 0; nb < 8; ++nb) O[mb][nb] = (f32x4){0.f, 0.f, 0.f, 0.f};
    float m_i[4] = {-INFINITY, -INFINITY, -INFINITY, -INFINITY};
    float l_i[4] = {0.f, 0.f, 0.f, 0.f};

    // S-frag swizzled granule positions (per-lane constants)
    const int plo = q4 ^ (l15 & 7);
    const int phi = plo ^ 4;

    const int nkt = 2 * qt + 2;
    for (int kt = 0; kt < nkt; ++kt) {
        const int k0 = kt * 32;

        // ---- B0: previous PV done; LDS safe to overwrite ----
        __syncthreads();

        // ---- issue all staging DMAs (17 per thread, in flight together) ----
#pragma unroll
        for (int it = 0; it < 9; ++it) {           // K: 2304 granules
            const int idx = tid + it * 256;
            const int key = idx / 72;
            const int gp  = idx - key * 72;
            const int u   = (gp & ~7) | ((gp & 7) ^ (key & 7));
            const void* src = (u < 64)
                ? (const void*)(ckv   + ((long)(b * S_LEN + k0 + key) * 576 + u * 8))
                : (const void*)(krope + ((long)(b * S_LEN + k0 + key) * 64 + (u - 64) * 8));
            gl2lds16(src, (char*)K_lds + ((it * 256 + w * 64) << 4));
        }
#pragma unroll
        for (int it = 0; it < 8; ++it) {           // VT: 2048 granules
            const int idx = tid + it * 256;
            const int c = idx >> 2, gl = idx & 3;
            const int gg = gl ^ ((c >> 1) & 3);
            const void* src = VT_g + ((long)(b * 512 + c) * S_LEN + k0 + gg * 8);
            gl2lds16(src, (char*)VT_lds + ((it * 256 + w * 64) << 4));
        }

        // ---- B1: drain DMA (vmcnt(0) at barrier), data visible ----
        __syncthreads();

        // ---- S-phase: rows w*16..+16 x 32 keys ----
        f32x4 s0 = {0.f, 0.f, 0.f, 0.f}, s1 = s0;
        {
            const unsigned short* krow0 = K_lds + l15 * 576;
            const unsigned short* krow1 = K_lds + (16 + l15) * 576;
#pragma unroll
            for (int kb = 0; kb < 18; ++kb) {
                const int p = (kb >> 1) * 8 + ((kb & 1) ? phi : plo);
                s16x8 k0f = *(const s16x8*)(krow0 + p * 8);
                s16x8 k1f = *(const s16x8*)(krow1 + p * 8);
                s0 = __builtin_amdgcn_mfma_f32_16x16x32_bf16(qf[kb], k0f, s0, 0, 0, 0);
                s1 = __builtin_amdgcn_mfma_f32_16x16x32_bf16(qf[kb], k1f, s1, 0, 0, 0);
            }
        }
#pragma unroll
        for (int r = 0; r < 4; ++r) { s0[r] *= scale; s1[r] *= scale; }
        if (kt >= 2 * qt) {  // diagonal tiles: causal mask
#pragma unroll
            for (int r = 0; r < 4; ++r) {
                int qg = q0 + w * 16 + q4 * 4 + r;
                if (k0 + l15 > qg)      s0[r] = -INFINITY;
                if (k0 + 16 + l15 > qg) s1[r] = -INFINITY;
            }
        }
        // online softmax + P write
#pragma unroll
        for (int r = 0; r < 4; ++r) {
            float mx = fmaxf(s0[r], s1[r]);
#pragma unroll
            for (int off = 1; off < 16; off <<= 1) mx = fmaxf(mx, __shfl_xor(mx, off, 64));
            const float mn = fmaxf(m_i[r], mx);
            const float al = __expf(m_i[r] - mn);   // first iter: exp(-inf)=0
            m_i[r] = mn;
            const float p0 = __expf(s0[r] - mn);
            const float p1 = __expf(s1[r] - mn);
            float ps = p0 + p1;
#pragma unroll
            for (int off = 1; off < 16; off <<= 1) ps += __shfl_xor(ps, off, 64);
            l_i[r] = l_i[r] * al + ps;
            const int row = w * 16 + q4 * 4 + r;
            P_lds[row * 40 + l15]      = f2b(p0);
            P_lds[row * 40 + 16 + l15] = f2b(p1);
            if (l15 == 0) af_lds[row] = al;
        }

        // ---- B2: P + alpha visible ----
        __syncthreads();

        // ---- PV-phase: all 64 rows x c-chunk [w*128, (w+1)*128) ----
#pragma unroll
        for (int mb = 0; mb < 4; ++mb) {
#pragma unroll
            for (int r = 0; r < 4; ++r) {
                const float al = af_lds[mb * 16 + q4 * 4 + r];
#pragma unroll
                for (int nb = 0; nb < 8; ++nb) O[mb][nb][r] *= al;
            }
        }
        s16x8 pf[4];
#pragma unroll
        for (int mb = 0; mb < 4; ++mb)
            pf[mb] = *(const s16x8*)&P_lds[(mb * 16 + l15) * 40 + q4 * 8];
#pragma unroll
        for (int nb = 0; nb < 8; ++nb) {
            const int c = w * 128 + nb * 16 + l15;
            const int gs = q4 ^ ((c >> 1) & 3);
            s16x8 vf = *(const s16x8*)&VT_lds[c * 32 + gs * 8];
#pragma unroll
            for (int mb = 0; mb < 4; ++mb)
                O[mb][nb] = __builtin_amdgcn_mfma_f32_16x16x32_bf16(pf[mb], vf, O[mb][nb], 0, 0, 0);
        }
    }

    // epilogue: O /= l, store bf16
    __syncthreads();
#pragma unroll
    for (int r = 0; r < 4; ++r)
        if (l15 == 0) af_lds[w * 16 + q4 * 4 + r] = l_i[r];
    __syncthreads();
#pragma unroll
    for (int mb = 0; mb < 4; ++mb) {
#pragma unroll
        for (int r = 0; r < 4; ++r) {
            const float inv = 1.0f / af_lds[mb * 16 + q4 * 4 + r];
            const long rowbase = ((long)bh * S_LEN + q0 + mb * 16 + q4 * 4 + r) * 512;
#pragma unroll
            for (int nb = 0; nb < 8; ++nb)
                attn_out[rowbase + w * 128 + nb * 16 + l15] = f2b(O[mb][nb][r] * inv);
        }
    }
}

// ---------------------------------------------------------------------------
extern "C" void kernel_launch(void* const* d_in, const int* in_sizes, int n_in,
                              void* d_out, int out_size, void* d_ws, size_t ws_size,
                              hipStream_t stream)
{
    (void)in_sizes; (void)n_in; (void)out_size; (void)ws_size;
    const float* hs_f       = (const float*)d_in[0];
    const int*   pos        = (const int*)d_in[1];
    // d_in[2] = attention_mask (causal, recomputed analytically) - unused
    const float* Wq_down_f  = (const float*)d_in[3];
    const float* q_ln_w_f   = (const float*)d_in[4];
    const float* Wq_up_f    = (const float*)d_in[5];
    const float* Wkv_down_f = (const float*)d_in[6];
    const float* Wkv_up_f   = (const float*)d_in[7];
    const float* Wo_f       = (const float*)d_in[8];
    float* out = (float*)d_out;

    // workspace layout (bf16 elements). out2 aliases q (dead after step 7).
    unsigned short* ws    = (unsigned short*)d_ws;
    unsigned short* ql    = ws;                        // 4096*1536
    unsigned short* q     = ql    + 4096L * 1536;      // 4096*3072
    unsigned short* out2  = q;                         // 4096*2048 (alias)
    unsigned short* ckv   = q     + 4096L * 3072;      // 4096*576
    unsigned short* krope = ckv   + 4096L * 576;       // 4096*64
    unsigned short* qrope = krope + 4096L * 64;        // 32*2048*64
    unsigned short* qabsT = qrope + 32L * 2048 * 64;   // 16*512*128
    unsigned short* qabs  = qabsT + 16L * 512 * 128;   // 32*2048*512
    unsigned short* attno = qabs  + 32L * 2048 * 512;  // 32*2048*512
    unsigned short* hs    = attno + 32L * 2048 * 512;  // 4096*2048
    unsigned short* Wqd   = hs    + 4096L * 2048;      // 1536*2048
    unsigned short* qlnw  = Wqd   + 1536L * 2048;      // 1536
    unsigned short* Wqu   = qlnw  + 1536;              // 3072*1536
    unsigned short* Wkvd  = Wqu   + 3072L * 1536;      // 576*2048
    unsigned short* Wkvu  = Wkvd  + 576L * 2048;       // 16*256*512
    unsigned short* Wob   = Wkvu  + 16L * 256 * 512;   // 2048*2048
    unsigned short* VTg   = Wob   + 2048L * 2048;      // 2*512*2048

    // 0) fp32 -> bf16 input conversion
    f32_to_bf16<<<4096, 256, 0, stream>>>(hs_f,       hs,   4096L * 2048);
    f32_to_bf16<<<3072, 256, 0, stream>>>(Wq_down_f,  Wqd,  1536L * 2048);
    f32_to_bf16<<<2,    256, 0, stream>>>(q_ln_w_f,   qlnw, 1536L);
    f32_to_bf16<<<4096, 256, 0, stream>>>(Wq_up_f,    Wqu,  3072L * 1536);
    f32_to_bf16<<<1152, 256, 0, stream>>>(Wkv_down_f, Wkvd, 576L * 2048);
    f32_to_bf16<<<2048, 256, 0, stream>>>(Wkv_up_f,   Wkvu, 16L * 256 * 512);
    f32_to_bf16<<<4096, 256, 0, stream>>>(Wo_f,       Wob,  2048L * 2048);

    // 1) ql = hs @ Wq_down^T   (4096x1536, K=2048)
    gemm_abt<unsigned short><<<dim3(64, 24, 1), 256, 0, stream>>>(hs, Wqd, ql,
        2048, 2048, 2048, 1536, 0, 0, 0, 0, 0, 0);
    // 2) RMSNorm(ql)
    rmsnorm_k<<<4096, 256, 0, stream>>>(ql, qlnw);
    // 3) q = ql @ Wq_up^T      (4096x3072, K=1536)
    gemm_abt<unsigned short><<<dim3(64, 48, 1), 256, 0, stream>>>(ql, Wqu, q,
        1536, 1536, 1536, 3072, 0, 0, 0, 0, 0, 0);
    // 4) ckv = hs @ Wkv_down^T (4096x576, K=2048)
    gemm_abt<unsigned short><<<dim3(64, 9, 1), 256, 0, stream>>>(hs, Wkvd, ckv,
        2048, 2048, 2048, 576, 0, 0, 0, 0, 0, 0);
    // 5) RoPE on q (per head) and k
    rope_k<<<4096, 512, 0, stream>>>(q, ckv, pos, qrope, krope);
    // 5b) VT_g[b][c][key] = ckv[b][key][c]
    transpose_ckv<<<dim3(32, 8, 2), 256, 0, stream>>>(ckv, VTg);
    // 6) transpose q_absorb -> (h, c, n)
    transpose_qabsorb<<<4096, 256, 0, stream>>>(Wkvu, qabsT);
    // 7) q_abs[b,h] = q_nope[b,h] @ q_absorbT[h]^T  (2048x512, K=128), batched 32
    gemm_abt<unsigned short><<<dim3(32, 8, 32), 256, 0, stream>>>(q, qabsT, qabs,
        128, 3072, 128, 512,
        2048L * 3072, 192, 0, 512L * 128, 16L * 2048 * 512, 2048L * 512);
    // 8) MFMA flash attention -> attn_out (B,NH,S,512)
    flash_mfma<<<dim3(32, 32, 1), 256, 0, stream>>>(qabs, qrope, ckv, krope, VTg, attno);
    // 9) out2 = attn_out @ out_absorb^T per head (2048x128, K=512), batched 32
    gemm_abt<unsigned short><<<dim3(32, 2, 32), 256, 0, stream>>>(attno, Wkvu + 128L * 512, out2,
        512, 512, 512, 2048,
        16L * 2048 * 512, 2048L * 512, 0, 256L * 512, 2048L * 2048, 128);
    // 10) out = out2 @ Wo^T    (4096x2048, K=2048), fp32 output
    gemm_abt<float><<<dim3(64, 32, 1), 256, 0, stream>>>(out2, Wob, out,
        2048, 2048, 2048, 2048, 0, 0, 0, 0, 0, 0);
}

// Round 5
// 1961.307 us; speedup vs baseline: 3.7145x; 1.0043x over previous
//
#include <hip/hip_runtime.h>
#include <cstdint>

// Problem constants (MicroCortexMLA): B=2, S=2048, H=2048, NH=16,
// NOPE=128, ROPE=64, VD=128, QLORA=1536, KVLORA=512, theta=1e6, eps=1e-6
// Harness dtypes: fp32 inputs (converted to bf16 in ws), int32 pos, fp32 out.
#define S_LEN 2048
#define NH_N  16

typedef short s16x8 __attribute__((ext_vector_type(8)));
typedef unsigned short u16x8 __attribute__((ext_vector_type(8)));
typedef float f32x4 __attribute__((ext_vector_type(4)));

__device__ __forceinline__ float b2f(unsigned short u) {
    return __uint_as_float(((uint32_t)u) << 16);
}
// round-to-nearest-even f32 -> bf16
__device__ __forceinline__ unsigned short f2b(float f) {
    uint32_t x = __float_as_uint(f);
    x += 0x7fffu + ((x >> 16) & 1u);
    return (unsigned short)(x >> 16);
}

__device__ __forceinline__ void cstore(unsigned short* p, float v) { *p = f2b(v); }
__device__ __forceinline__ void cstore(float* p, float v) { *p = v; }

// async global->LDS DMA, 16B per lane. LDS dst is wave-uniform base; HW adds
// lane*16. Tracked by vmcnt; __syncthreads() drains it.
__device__ __forceinline__ void gl2lds16(const void* g, void* l) {
    __builtin_amdgcn_global_load_lds(
        (const __attribute__((address_space(1))) unsigned int*)g,
        (__attribute__((address_space(3))) unsigned int*)l, 16, 0, 0);
}

// ---------------------------------------------------------------------------
// fp32 -> bf16 conversion, vectorized x4, grid-stride. n % 4 == 0.
// ---------------------------------------------------------------------------
__global__ __launch_bounds__(256) void f32_to_bf16(const float* __restrict__ in,
                                                   unsigned short* __restrict__ out,
                                                   long n)
{
    const long nv = n >> 2;
    long i = (long)blockIdx.x * blockDim.x + threadIdx.x;
    const long stride = (long)gridDim.x * blockDim.x;
    for (; i < nv; i += stride) {
        float4 v = ((const float4*)in)[i];
        ushort4 o;
        o.x = f2b(v.x); o.y = f2b(v.y); o.z = f2b(v.z); o.w = f2b(v.w);
        ((ushort4*)out)[i] = o;
    }
}

// ---------------------------------------------------------------------------
// C = A @ B^T, m97-style: 128x128 block tile, BK=32, LDS staged via
// global_load_lds (16B/lane), 2-barrier K-loop. block 256 = 4 waves; wave w
// computes 64x64 at (w>>1, w&1) quadrant = 4x4 MFMA accs.
// LDS granule swizzle: position gp of row holds source granule
// gp ^ ((row ^ (row>>2)) & 3)  -> frag ds_read_b128 2-way max (free).
// Stores guarded by col < Nlim (B rows beyond N read adjacent ws, harmless).
// Batched over blockIdx.z = b*16+h. M%128==0, K%32==0, 16B alignment.
// ---------------------------------------------------------------------------
template <typename CT>
__global__ __launch_bounds__(256) void gemm128(
    const unsigned short* __restrict__ A, const unsigned short* __restrict__ B,
    CT* __restrict__ C,
    int K, int lda, int ldb, int ldc, int Nlim,
    long sAb, long sAh, long sBb, long sBh, long sCb, long sCh)
{
    __shared__ unsigned short Alds[128 * 32];
    __shared__ unsigned short Blds[128 * 32];
    const int z = blockIdx.z, b = z >> 4, h = z & 15;
    A += (long)b * sAb + (long)h * sAh;
    B += (long)b * sBb + (long)h * sBh;
    C += (long)b * sCb + (long)h * sCh;
    const int tid = threadIdx.x;
    const int lane = tid & 63, w = tid >> 6;
    const int l15 = lane & 15, q4 = lane >> 4;
    const int m0 = blockIdx.x * 128, n0 = blockIdx.y * 128;
    const int wm = (w >> 1) * 64, wn = (w & 1) * 64;

    // per-thread staging constants (2 granules per tile)
    int srow[2], sgc[2];
#pragma unroll
    for (int it = 0; it < 2; ++it) {
        const int g = it * 256 + tid;
        const int row = g >> 2, gp = g & 3;
        srow[it] = row;
        sgc[it] = gp ^ ((row ^ (row >> 2)) & 3);
    }
    // per-thread frag read offsets
    int aoff[4], boff[4];
#pragma unroll
    for (int i = 0; i < 4; ++i) {
        const int ra = wm + i * 16 + l15;
        aoff[i] = ra * 32 + (q4 ^ ((ra ^ (ra >> 2)) & 3)) * 8;
        const int rb = wn + i * 16 + l15;
        boff[i] = rb * 32 + (q4 ^ ((rb ^ (rb >> 2)) & 3)) * 8;
    }

    f32x4 acc[4][4];
#pragma unroll
    for (int i = 0; i < 4; ++i)
#pragma unroll
        for (int j = 0; j < 4; ++j) acc[i][j] = (f32x4){0.f, 0.f, 0.f, 0.f};

    for (int k0 = 0; k0 < K; k0 += 32) {
        __syncthreads();  // previous iter's frag reads done
#pragma unroll
        for (int it = 0; it < 2; ++it) {
            gl2lds16(A + (long)(m0 + srow[it]) * lda + k0 + sgc[it] * 8,
                     (char*)Alds + ((it * 256 + w * 64) << 4));
            gl2lds16(B + (long)(n0 + srow[it]) * ldb + k0 + sgc[it] * 8,
                     (char*)Blds + ((it * 256 + w * 64) << 4));
        }
        __syncthreads();  // drain DMA
        s16x8 af[4], bf[4];
#pragma unroll
        for (int i = 0; i < 4; ++i) {
            af[i] = *(const s16x8*)(Alds + aoff[i]);
            bf[i] = *(const s16x8*)(Blds + boff[i]);
        }
#pragma unroll
        for (int i = 0; i < 4; ++i)
#pragma unroll
            for (int j = 0; j < 4; ++j)
                acc[i][j] = __builtin_amdgcn_mfma_f32_16x16x32_bf16(af[i], bf[j], acc[i][j], 0, 0, 0);
    }

#pragma unroll
    for (int i = 0; i < 4; ++i) {
        const int row0 = m0 + wm + i * 16 + q4 * 4;
#pragma unroll
        for (int j = 0; j < 4; ++j) {
            const int col = n0 + wn + j * 16 + l15;
            if (col < Nlim) {
#pragma unroll
                for (int r = 0; r < 4; ++r)
                    cstore(&C[(long)(row0 + r) * ldc + col], acc[i][j][r]);
            }
        }
    }
}

// ---------------------------------------------------------------------------
// In-place RMSNorm over rows of 1536, one block per row.
// ---------------------------------------------------------------------------
__global__ __launch_bounds__(256) void rmsnorm_k(unsigned short* __restrict__ ql,
                                                 const unsigned short* __restrict__ w)
{
    const long base = (long)blockIdx.x * 1536;
    const int tid = threadIdx.x;
    float v[6];
    float ss = 0.f;
#pragma unroll
    for (int i = 0; i < 6; ++i) {
        v[i] = b2f(ql[base + tid + i * 256]);
        ss += v[i] * v[i];
    }
#pragma unroll
    for (int off = 32; off; off >>= 1) ss += __shfl_xor(ss, off, 64);
    __shared__ float red[4];
    if ((tid & 63) == 0) red[tid >> 6] = ss;
    __syncthreads();
    const float tot = red[0] + red[1] + red[2] + red[3];
    const float r = rsqrtf(tot * (1.0f / 1536.0f) + 1e-6f);
#pragma unroll
    for (int i = 0; i < 6; ++i) {
        const int idx = tid + i * 256;
        ql[base + idx] = f2b(v[i] * r * b2f(w[idx]));
    }
}

// ---------------------------------------------------------------------------
// RoPE for q (per head) and k (reference's permuted layout, consistent q/k).
// ---------------------------------------------------------------------------
__global__ __launch_bounds__(512) void rope_k(
    const unsigned short* __restrict__ q, const unsigned short* __restrict__ ckv,
    const int* __restrict__ pos_ids,
    unsigned short* __restrict__ q_rope, unsigned short* __restrict__ krope)
{
    const int bs = blockIdx.x;
    const int b = bs >> 11, s = bs & 2047;
    const int t = threadIdx.x;
    const int j = t & 31, h = t >> 5;
    const float pos = (float)pos_ids[bs];
    const float invf = __expf(-(float)j * 0.4317347f);  // ln(1e6)/32
    float sn, cs;
    sincosf(pos * invf, &sn, &cs);
    const unsigned short* x = q + (long)bs * 3072 + h * 192 + 128;
    const float x0 = b2f(x[2 * j]), x1 = b2f(x[2 * j + 1]);
    const long ob = ((long)(b * NH_N + h) * S_LEN + s) * 64;
    q_rope[ob + j]      = f2b(x0 * cs - x1 * sn);
    q_rope[ob + 32 + j] = f2b(x1 * cs + x0 * sn);
    if (h == 0) {
        const unsigned short* y = ckv + (long)bs * 576 + 512;
        const float y0 = b2f(y[2 * j]), y1 = b2f(y[2 * j + 1]);
        const long ob2 = (long)bs * 64;
        krope[ob2 + j]      = f2b(y0 * cs - y1 * sn);
        krope[ob2 + 32 + j] = f2b(y1 * cs + y0 * sn);
    }
}

// qT[h][c][n] = Wkv_up[(h*256+n)*512 + c]
__global__ __launch_bounds__(256) void transpose_qabsorb(
    const unsigned short* __restrict__ Wkv_up, unsigned short* __restrict__ qT)
{
    const int idx = blockIdx.x * 256 + threadIdx.x;
    const int n = idx & 127;
    const int c = (idx >> 7) & 511;
    const int h = idx >> 16;
    qT[idx] = Wkv_up[((long)(h * 256 + n)) * 512 + c];
}

// ---------------------------------------------------------------------------
// VT_g[b][c][key] = ckv[b][key][c]  (c < 512) — V^T for the PV MFMA B-frags.
// Tiled 64x64 transpose through LDS. grid (32 keyblk, 8 cblk, 2 b).
// ---------------------------------------------------------------------------
__global__ __launch_bounds__(256) void transpose_ckv(
    const unsigned short* __restrict__ ckv, unsigned short* __restrict__ VT_g)
{
    __shared__ unsigned short t[64][72];  // +8 pad
    const int k0 = blockIdx.x * 64, c0 = blockIdx.y * 64, b = blockIdx.z;
    const int tid = threadIdx.x;
#pragma unroll
    for (int it = 0; it < 2; ++it) {
        int idx = tid + it * 256;  // 512 tasks: 64 rows x 8 granules
        int row = idx >> 3, g = idx & 7;
        *(s16x8*)&t[row][g * 8] =
            *(const s16x8*)(ckv + ((long)(b * S_LEN + k0 + row) * 576 + c0 + g * 8));
    }
    __syncthreads();
#pragma unroll
    for (int it = 0; it < 2; ++it) {
        int idx = tid + it * 256;  // 512 tasks: 64 c x 8 key-granules
        int c = idx >> 3, g = idx & 7;
        u16x8 v;
#pragma unroll
        for (int j = 0; j < 8; ++j) v[j] = t[g * 8 + j][c];
        *(u16x8*)(VT_g + ((long)(b * 512 + c0 + c) * S_LEN + k0 + g * 8)) = v;
    }
}

// ---------------------------------------------------------------------------
// MFMA flash attention in the 576-dim latent space (512 c + 64 rope).
// grid (32 bh, 32 y), qt = 31-y (long blocks dispatch first). block 256.
// K-tile staged via global_load_lds DMA with source granule swizzle
//   (gp&7)^(key&7) -> S-frag reads 2-way max. VT B-frags are loaded DIRECTLY
// from global VT_g (per-wave-private data; 4 lanes x 16B = full 64B lines),
// prefetched at loop top so they drain with the K DMA at the same barrier.
// LDS = 42 KB -> 3 blocks/CU.
// S-phase: wave w: rows w*16..+16 x 32 keys, Q-frags (18) resident in regs.
// Online softmax in D-layout (row=quad*4+reg); P via LDS round-trip.
// PV-phase: wave w: ALL 64 rows x c-chunk [w*128,(w+1)*128); O = 128 acc.
// ---------------------------------------------------------------------------
__global__ __launch_bounds__(256, 3) void flash_mfma(
    const unsigned short* __restrict__ qabs,  const unsigned short* __restrict__ qrope,
    const unsigned short* __restrict__ ckv,   const unsigned short* __restrict__ krope,
    const unsigned short* __restrict__ VT_g,  unsigned short* __restrict__ attn_out)
{
    __shared__ unsigned short K_lds[32 * 576];   // source-swizzled granules
    __shared__ unsigned short P_lds[64 * 40];    // 64 rows x (32 + 8 pad)
    __shared__ float af_lds[64];                 // alpha per row; reused for l

    const float scale = 0.07216878364870323f;  // 1/sqrt(192)
    const int tid = threadIdx.x;
    const int lane = tid & 63, w = tid >> 6;
    const int l15 = lane & 15, q4 = lane >> 4;
    const int bh = blockIdx.x;
    const int qt = 31 - blockIdx.y;           // long tiles first
    const int b = bh >> 4;
    const int q0 = qt * 64;

    // Q fragments: rows q0 + w*16 + l15, dims kb*32 + q4*8 (+j)
    s16x8 qf[18];
    {
        const unsigned short* qa = qabs + ((long)bh * S_LEN + q0 + w * 16 + l15) * 512 + q4 * 8;
#pragma unroll
        for (int kb = 0; kb < 16; ++kb) qf[kb] = *(const s16x8*)(qa + kb * 32);
        const unsigned short* qr = qrope + ((long)bh * S_LEN + q0 + w * 16 + l15) * 64 + q4 * 8;
        qf[16] = *(const s16x8*)(qr);
        qf[17] = *(const s16x8*)(qr + 32);
    }

    f32x4 O[4][8];
#pragma unroll
    for (int mb = 0; mb < 4; ++mb)
#pragma unroll
        for (int nb = 0; nb < 8; ++nb) O[mb][nb] = (f32x4){0.f, 0.f, 0.f, 0.f};
    float m_i[4] = {-INFINITY, -INFINITY, -INFINITY, -INFINITY};
    float l_i[4] = {0.f, 0.f, 0.f, 0.f};

    // S-frag swizzled granule positions (per-lane constants)
    const int plo = q4 ^ (l15 & 7);
    const int phi = plo ^ 4;
    // VT direct-load base: lane covers c = w*128 + nb*16 + l15, k = q4*8..+8
    const unsigned short* vt_base = VT_g + ((long)(b * 512 + w * 128 + l15)) * S_LEN + q4 * 8;

    const int nkt = 2 * qt + 2;
    for (int kt = 0; kt < nkt; ++kt) {
        const int k0 = kt * 32;

        // ---- B0: previous PV done; LDS safe to overwrite ----
        __syncthreads();

        // ---- issue K staging DMAs (9 per thread, in flight together) ----
#pragma unroll
        for (int it = 0; it < 9; ++it) {           // K: 2304 granules
            const int idx = tid + it * 256;
            const int key = idx / 72;
            const int gp  = idx - key * 72;
            const int u   = (gp & ~7) | ((gp & 7) ^ (key & 7));
            const void* src = (u < 64)
                ? (const void*)(ckv   + ((long)(b * S_LEN + k0 + key) * 576 + u * 8))
                : (const void*)(krope + ((long)(b * S_LEN + k0 + key) * 64 + (u - 64) * 8));
            gl2lds16(src, (char*)K_lds + ((it * 256 + w * 64) << 4));
        }
        // ---- prefetch VT B-frags from global (drain shared with DMA) ----
        s16x8 vf[8];
#pragma unroll
        for (int nb = 0; nb < 8; ++nb)
            vf[nb] = *(const s16x8*)(vt_base + (long)nb * 16 * S_LEN + k0);

        // ---- B1: drain DMA + loads, data visible ----
        __syncthreads();

        // ---- S-phase: rows w*16..+16 x 32 keys ----
        f32x4 s0 = {0.f, 0.f, 0.f, 0.f}, s1 = s0;
        {
            const unsigned short* krow0 = K_lds + l15 * 576;
            const unsigned short* krow1 = K_lds + (16 + l15) * 576;
#pragma unroll
            for (int kb = 0; kb < 18; ++kb) {
                const int p = (kb >> 1) * 8 + ((kb & 1) ? phi : plo);
                s16x8 k0f = *(const s16x8*)(krow0 + p * 8);
                s16x8 k1f = *(const s16x8*)(krow1 + p * 8);
                s0 = __builtin_amdgcn_mfma_f32_16x16x32_bf16(qf[kb], k0f, s0, 0, 0, 0);
                s1 = __builtin_amdgcn_mfma_f32_16x16x32_bf16(qf[kb], k1f, s1, 0, 0, 0);
            }
        }
#pragma unroll
        for (int r = 0; r < 4; ++r) { s0[r] *= scale; s1[r] *= scale; }
        if (kt >= 2 * qt) {  // diagonal tiles: causal mask
#pragma unroll
            for (int r = 0; r < 4; ++r) {
                int qg = q0 + w * 16 + q4 * 4 + r;
                if (k0 + l15 > qg)      s0[r] = -INFINITY;
                if (k0 + 16 + l15 > qg) s1[r] = -INFINITY;
            }
        }
        // online softmax + P write
#pragma unroll
        for (int r = 0; r < 4; ++r) {
            float mx = fmaxf(s0[r], s1[r]);
#pragma unroll
            for (int off = 1; off < 16; off <<= 1) mx = fmaxf(mx, __shfl_xor(mx, off, 64));
            const float mn = fmaxf(m_i[r], mx);
            const float al = __expf(m_i[r] - mn);   // first iter: exp(-inf)=0
            m_i[r] = mn;
            const float p0 = __expf(s0[r] - mn);
            const float p1 = __expf(s1[r] - mn);
            float ps = p0 + p1;
#pragma unroll
            for (int off = 1; off < 16; off <<= 1) ps += __shfl_xor(ps, off, 64);
            l_i[r] = l_i[r] * al + ps;
            const int row = w * 16 + q4 * 4 + r;
            P_lds[row * 40 + l15]      = f2b(p0);
            P_lds[row * 40 + 16 + l15] = f2b(p1);
            if (l15 == 0) af_lds[row] = al;
        }

        // ---- B2: P + alpha visible ----
        __syncthreads();

        // ---- PV-phase: all 64 rows x c-chunk [w*128, (w+1)*128) ----
#pragma unroll
        for (int mb = 0; mb < 4; ++mb) {
#pragma unroll
            for (int r = 0; r < 4; ++r) {
                const float al = af_lds[mb * 16 + q4 * 4 + r];
#pragma unroll
                for (int nb = 0; nb < 8; ++nb) O[mb][nb][r] *= al;
            }
        }
        s16x8 pf[4];
#pragma unroll
        for (int mb = 0; mb < 4; ++mb)
            pf[mb] = *(const s16x8*)&P_lds[(mb * 16 + l15) * 40 + q4 * 8];
#pragma unroll
        for (int nb = 0; nb < 8; ++nb) {
#pragma unroll
            for (int mb = 0; mb < 4; ++mb)
                O[mb][nb] = __builtin_amdgcn_mfma_f32_16x16x32_bf16(pf[mb], vf[nb], O[mb][nb], 0, 0, 0);
        }
    }

    // epilogue: O /= l, store bf16
    __syncthreads();
#pragma unroll
    for (int r = 0; r < 4; ++r)
        if (l15 == 0) af_lds[w * 16 + q4 * 4 + r] = l_i[r];
    __syncthreads();
#pragma unroll
    for (int mb = 0; mb < 4; ++mb) {
#pragma unroll
        for (int r = 0; r < 4; ++r) {
            const float inv = 1.0f / af_lds[mb * 16 + q4 * 4 + r];
            const long rowbase = ((long)bh * S_LEN + q0 + mb * 16 + q4 * 4 + r) * 512;
#pragma unroll
            for (int nb = 0; nb < 8; ++nb)
                attn_out[rowbase + w * 128 + nb * 16 + l15] = f2b(O[mb][nb][r] * inv);
        }
    }
}

// ---------------------------------------------------------------------------
extern "C" void kernel_launch(void* const* d_in, const int* in_sizes, int n_in,
                              void* d_out, int out_size, void* d_ws, size_t ws_size,
                              hipStream_t stream)
{
    (void)in_sizes; (void)n_in; (void)out_size; (void)ws_size;
    const float* hs_f       = (const float*)d_in[0];
    const int*   pos        = (const int*)d_in[1];
    // d_in[2] = attention_mask (causal, recomputed analytically) - unused
    const float* Wq_down_f  = (const float*)d_in[3];
    const float* q_ln_w_f   = (const float*)d_in[4];
    const float* Wq_up_f    = (const float*)d_in[5];
    const float* Wkv_down_f = (const float*)d_in[6];
    const float* Wkv_up_f   = (const float*)d_in[7];
    const float* Wo_f       = (const float*)d_in[8];
    float* out = (float*)d_out;

    // workspace layout (bf16 elements). out2 aliases q (dead after step 7).
    unsigned short* ws    = (unsigned short*)d_ws;
    unsigned short* ql    = ws;                        // 4096*1536
    unsigned short* q     = ql    + 4096L * 1536;      // 4096*3072
    unsigned short* out2  = q;                         // 4096*2048 (alias)
    unsigned short* ckv   = q     + 4096L * 3072;      // 4096*576
    unsigned short* krope = ckv   + 4096L * 576;       // 4096*64
    unsigned short* qrope = krope + 4096L * 64;        // 32*2048*64
    unsigned short* qabsT = qrope + 32L * 2048 * 64;   // 16*512*128
    unsigned short* qabs  = qabsT + 16L * 512 * 128;   // 32*2048*512
    unsigned short* attno = qabs  + 32L * 2048 * 512;  // 32*2048*512
    unsigned short* hs    = attno + 32L * 2048 * 512;  // 4096*2048
    unsigned short* Wqd   = hs    + 4096L * 2048;      // 1536*2048
    unsigned short* qlnw  = Wqd   + 1536L * 2048;      // 1536
    unsigned short* Wqu   = qlnw  + 1536;              // 3072*1536
    unsigned short* Wkvd  = Wqu   + 3072L * 1536;      // 576*2048
    unsigned short* Wkvu  = Wkvd  + 576L * 2048;       // 16*256*512
    unsigned short* Wob   = Wkvu  + 16L * 256 * 512;   // 2048*2048
    unsigned short* VTg   = Wob   + 2048L * 2048;      // 2*512*2048

    // 0) fp32 -> bf16 input conversion
    f32_to_bf16<<<4096, 256, 0, stream>>>(hs_f,       hs,   4096L * 2048);
    f32_to_bf16<<<3072, 256, 0, stream>>>(Wq_down_f,  Wqd,  1536L * 2048);
    f32_to_bf16<<<2,    256, 0, stream>>>(q_ln_w_f,   qlnw, 1536L);
    f32_to_bf16<<<4096, 256, 0, stream>>>(Wq_up_f,    Wqu,  3072L * 1536);
    f32_to_bf16<<<1152, 256, 0, stream>>>(Wkv_down_f, Wkvd, 576L * 2048);
    f32_to_bf16<<<2048, 256, 0, stream>>>(Wkv_up_f,   Wkvu, 16L * 256 * 512);
    f32_to_bf16<<<4096, 256, 0, stream>>>(Wo_f,       Wob,  2048L * 2048);

    // 1) ql = hs @ Wq_down^T   (4096x1536, K=2048)
    gemm128<unsigned short><<<dim3(32, 12, 1), 256, 0, stream>>>(hs, Wqd, ql,
        2048, 2048, 2048, 1536, 1536, 0, 0, 0, 0, 0, 0);
    // 2) RMSNorm(ql)
    rmsnorm_k<<<4096, 256, 0, stream>>>(ql, qlnw);
    // 3) q = ql @ Wq_up^T      (4096x3072, K=1536)
    gemm128<unsigned short><<<dim3(32, 24, 1), 256, 0, stream>>>(ql, Wqu, q,
        1536, 1536, 1536, 3072, 3072, 0, 0, 0, 0, 0, 0);
    // 4) ckv = hs @ Wkv_down^T (4096x576, K=2048); Nlim guards last tile
    gemm128<unsigned short><<<dim3(32, 5, 1), 256, 0, stream>>>(hs, Wkvd, ckv,
        2048, 2048, 2048, 576, 576, 0, 0, 0, 0, 0, 0);
    // 5) RoPE on q (per head) and k
    rope_k<<<4096, 512, 0, stream>>>(q, ckv, pos, qrope, krope);
    // 5b) VT_g[b][c][key] = ckv[b][key][c]
    transpose_ckv<<<dim3(32, 8, 2), 256, 0, stream>>>(ckv, VTg);
    // 6) transpose q_absorb -> (h, c, n)
    transpose_qabsorb<<<4096, 256, 0, stream>>>(Wkvu, qabsT);
    // 7) q_abs[b,h] = q_nope[b,h] @ q_absorbT[h]^T  (2048x512, K=128), batched 32
    gemm128<unsigned short><<<dim3(16, 4, 32), 256, 0, stream>>>(q, qabsT, qabs,
        128, 3072, 128, 512, 512,
        2048L * 3072, 192, 0, 512L * 128, 16L * 2048 * 512, 2048L * 512);
    // 8) MFMA flash attention -> attn_out (B,NH,S,512)
    flash_mfma<<<dim3(32, 32, 1), 256, 0, stream>>>(qabs, qrope, ckv, krope, VTg, attno);
    // 9) out2 = attn_out @ out_absorb^T per head (2048x128, K=512), batched 32
    gemm128<unsigned short><<<dim3(16, 1, 32), 256, 0, stream>>>(attno, Wkvu + 128L * 512, out2,
        512, 512, 512, 2048, 128,
        16L * 2048 * 512, 2048L * 512, 0, 256L * 512, 2048L * 2048, 128);
    // 10) out = out2 @ Wo^T    (4096x2048, K=2048), fp32 output
    gemm128<float><<<dim3(32, 16, 1), 256, 0, stream>>>(out2, Wob, out,
        2048, 2048, 2048, 2048, 2048, 0, 0, 0, 0, 0, 0);
}

// Round 6
// 978.988 us; speedup vs baseline: 7.4416x; 2.0034x over previous
//
#include <hip/hip_runtime.h>
#include <cstdint>

// Problem constants (MicroCortexMLA): B=2, S=2048, H=2048, NH=16,
// NOPE=128, ROPE=64, VD=128, QLORA=1536, KVLORA=512, theta=1e6, eps=1e-6
// Harness dtypes: fp32 inputs (converted to bf16 in ws), int32 pos, fp32 out.
#define S_LEN 2048
#define NH_N  16

typedef short s16x8 __attribute__((ext_vector_type(8)));
typedef unsigned short u16x8 __attribute__((ext_vector_type(8)));
typedef float f32x4 __attribute__((ext_vector_type(4)));

__device__ __forceinline__ float b2f(unsigned short u) {
    return __uint_as_float(((uint32_t)u) << 16);
}
// round-to-nearest-even f32 -> bf16
__device__ __forceinline__ unsigned short f2b(float f) {
    uint32_t x = __float_as_uint(f);
    x += 0x7fffu + ((x >> 16) & 1u);
    return (unsigned short)(x >> 16);
}

__device__ __forceinline__ void cstore(unsigned short* p, float v) { *p = f2b(v); }
__device__ __forceinline__ void cstore(float* p, float v) { *p = v; }

// async global->LDS DMA, 16B per lane. LDS dst is wave-uniform base; HW adds
// lane*16. Tracked by vmcnt; __syncthreads() drains it.
__device__ __forceinline__ void gl2lds16(const void* g, void* l) {
    __builtin_amdgcn_global_load_lds(
        (const __attribute__((address_space(1))) unsigned int*)g,
        (__attribute__((address_space(3))) unsigned int*)l, 16, 0, 0);
}

// ---------------------------------------------------------------------------
// fp32 -> bf16 conversion, vectorized x4, grid-stride. n % 4 == 0.
// ---------------------------------------------------------------------------
__global__ __launch_bounds__(256) void f32_to_bf16(const float* __restrict__ in,
                                                   unsigned short* __restrict__ out,
                                                   long n)
{
    const long nv = n >> 2;
    long i = (long)blockIdx.x * blockDim.x + threadIdx.x;
    const long stride = (long)gridDim.x * blockDim.x;
    for (; i < nv; i += stride) {
        float4 v = ((const float4*)in)[i];
        ushort4 o;
        o.x = f2b(v.x); o.y = f2b(v.y); o.z = f2b(v.z); o.w = f2b(v.w);
        ((ushort4*)out)[i] = o;
    }
}

// ---------------------------------------------------------------------------
// C = A @ B^T, m97-style: 128x128 block tile, BK=32, LDS staged via
// global_load_lds (16B/lane), 2-barrier K-loop. block 256 = 4 waves; wave w
// computes 64x64 at (w>>1, w&1) quadrant = 4x4 MFMA accs.
// LDS granule swizzle: position gp of row holds source granule
// gp ^ ((row ^ (row>>2)) & 3)  -> frag ds_read_b128 2-way max (free).
// Stores guarded by col < Nlim (B rows beyond N read adjacent ws, harmless).
// Batched over blockIdx.z = b*16+h. M%128==0, K%32==0, 16B alignment.
// ---------------------------------------------------------------------------
template <typename CT>
__global__ __launch_bounds__(256) void gemm128(
    const unsigned short* __restrict__ A, const unsigned short* __restrict__ B,
    CT* __restrict__ C,
    int K, int lda, int ldb, int ldc, int Nlim,
    long sAb, long sAh, long sBb, long sBh, long sCb, long sCh)
{
    __shared__ unsigned short Alds[128 * 32];
    __shared__ unsigned short Blds[128 * 32];
    const int z = blockIdx.z, b = z >> 4, h = z & 15;
    A += (long)b * sAb + (long)h * sAh;
    B += (long)b * sBb + (long)h * sBh;
    C += (long)b * sCb + (long)h * sCh;
    const int tid = threadIdx.x;
    const int lane = tid & 63, w = tid >> 6;
    const int l15 = lane & 15, q4 = lane >> 4;
    const int m0 = blockIdx.x * 128, n0 = blockIdx.y * 128;
    const int wm = (w >> 1) * 64, wn = (w & 1) * 64;

    // per-thread staging constants (2 granules per tile)
    int srow[2], sgc[2];
#pragma unroll
    for (int it = 0; it < 2; ++it) {
        const int g = it * 256 + tid;
        const int row = g >> 2, gp = g & 3;
        srow[it] = row;
        sgc[it] = gp ^ ((row ^ (row >> 2)) & 3);
    }
    // per-thread frag read offsets
    int aoff[4], boff[4];
#pragma unroll
    for (int i = 0; i < 4; ++i) {
        const int ra = wm + i * 16 + l15;
        aoff[i] = ra * 32 + (q4 ^ ((ra ^ (ra >> 2)) & 3)) * 8;
        const int rb = wn + i * 16 + l15;
        boff[i] = rb * 32 + (q4 ^ ((rb ^ (rb >> 2)) & 3)) * 8;
    }

    f32x4 acc[4][4];
#pragma unroll
    for (int i = 0; i < 4; ++i)
#pragma unroll
        for (int j = 0; j < 4; ++j) acc[i][j] = (f32x4){0.f, 0.f, 0.f, 0.f};

    for (int k0 = 0; k0 < K; k0 += 32) {
        __syncthreads();  // previous iter's frag reads done
#pragma unroll
        for (int it = 0; it < 2; ++it) {
            gl2lds16(A + (long)(m0 + srow[it]) * lda + k0 + sgc[it] * 8,
                     (char*)Alds + ((it * 256 + w * 64) << 4));
            gl2lds16(B + (long)(n0 + srow[it]) * ldb + k0 + sgc[it] * 8,
                     (char*)Blds + ((it * 256 + w * 64) << 4));
        }
        __syncthreads();  // drain DMA
        s16x8 af[4], bf[4];
#pragma unroll
        for (int i = 0; i < 4; ++i) {
            af[i] = *(const s16x8*)(Alds + aoff[i]);
            bf[i] = *(const s16x8*)(Blds + boff[i]);
        }
#pragma unroll
        for (int i = 0; i < 4; ++i)
#pragma unroll
            for (int j = 0; j < 4; ++j)
                acc[i][j] = __builtin_amdgcn_mfma_f32_16x16x32_bf16(af[i], bf[j], acc[i][j], 0, 0, 0);
    }

#pragma unroll
    for (int i = 0; i < 4; ++i) {
        const int row0 = m0 + wm + i * 16 + q4 * 4;
#pragma unroll
        for (int j = 0; j < 4; ++j) {
            const int col = n0 + wn + j * 16 + l15;
            if (col < Nlim) {
#pragma unroll
                for (int r = 0; r < 4; ++r)
                    cstore(&C[(long)(row0 + r) * ldc + col], acc[i][j][r]);
            }
        }
    }
}

// ---------------------------------------------------------------------------
// In-place RMSNorm over rows of 1536, one block per row.
// ---------------------------------------------------------------------------
__global__ __launch_bounds__(256) void rmsnorm_k(unsigned short* __restrict__ ql,
                                                 const unsigned short* __restrict__ w)
{
    const long base = (long)blockIdx.x * 1536;
    const int tid = threadIdx.x;
    float v[6];
    float ss = 0.f;
#pragma unroll
    for (int i = 0; i < 6; ++i) {
        v[i] = b2f(ql[base + tid + i * 256]);
        ss += v[i] * v[i];
    }
#pragma unroll
    for (int off = 32; off; off >>= 1) ss += __shfl_xor(ss, off, 64);
    __shared__ float red[4];
    if ((tid & 63) == 0) red[tid >> 6] = ss;
    __syncthreads();
    const float tot = red[0] + red[1] + red[2] + red[3];
    const float r = rsqrtf(tot * (1.0f / 1536.0f) + 1e-6f);
#pragma unroll
    for (int i = 0; i < 6; ++i) {
        const int idx = tid + i * 256;
        ql[base + idx] = f2b(v[i] * r * b2f(w[idx]));
    }
}

// ---------------------------------------------------------------------------
// RoPE for q (per head) and k (reference's permuted layout, consistent q/k).
// ---------------------------------------------------------------------------
__global__ __launch_bounds__(512) void rope_k(
    const unsigned short* __restrict__ q, const unsigned short* __restrict__ ckv,
    const int* __restrict__ pos_ids,
    unsigned short* __restrict__ q_rope, unsigned short* __restrict__ krope)
{
    const int bs = blockIdx.x;
    const int b = bs >> 11, s = bs & 2047;
    const int t = threadIdx.x;
    const int j = t & 31, h = t >> 5;
    const float pos = (float)pos_ids[bs];
    const float invf = __expf(-(float)j * 0.4317347f);  // ln(1e6)/32
    float sn, cs;
    sincosf(pos * invf, &sn, &cs);
    const unsigned short* x = q + (long)bs * 3072 + h * 192 + 128;
    const float x0 = b2f(x[2 * j]), x1 = b2f(x[2 * j + 1]);
    const long ob = ((long)(b * NH_N + h) * S_LEN + s) * 64;
    q_rope[ob + j]      = f2b(x0 * cs - x1 * sn);
    q_rope[ob + 32 + j] = f2b(x1 * cs + x0 * sn);
    if (h == 0) {
        const unsigned short* y = ckv + (long)bs * 576 + 512;
        const float y0 = b2f(y[2 * j]), y1 = b2f(y[2 * j + 1]);
        const long ob2 = (long)bs * 64;
        krope[ob2 + j]      = f2b(y0 * cs - y1 * sn);
        krope[ob2 + 32 + j] = f2b(y1 * cs + y0 * sn);
    }
}

// qT[h][c][n] = Wkv_up[(h*256+n)*512 + c]
__global__ __launch_bounds__(256) void transpose_qabsorb(
    const unsigned short* __restrict__ Wkv_up, unsigned short* __restrict__ qT)
{
    const int idx = blockIdx.x * 256 + threadIdx.x;
    const int n = idx & 127;
    const int c = (idx >> 7) & 511;
    const int h = idx >> 16;
    qT[idx] = Wkv_up[((long)(h * 256 + n)) * 512 + c];
}

// ---------------------------------------------------------------------------
// VT_g[b][c][key] = ckv[b][key][c]  (c < 512) — V^T for the PV MFMA B-frags.
// Tiled 64x64 transpose through LDS. grid (32 keyblk, 8 cblk, 2 b).
// ---------------------------------------------------------------------------
__global__ __launch_bounds__(256) void transpose_ckv(
    const unsigned short* __restrict__ ckv, unsigned short* __restrict__ VT_g)
{
    __shared__ unsigned short t[64][72];  // +8 pad
    const int k0 = blockIdx.x * 64, c0 = blockIdx.y * 64, b = blockIdx.z;
    const int tid = threadIdx.x;
#pragma unroll
    for (int it = 0; it < 2; ++it) {
        int idx = tid + it * 256;  // 512 tasks: 64 rows x 8 granules
        int row = idx >> 3, g = idx & 7;
        *(s16x8*)&t[row][g * 8] =
            *(const s16x8*)(ckv + ((long)(b * S_LEN + k0 + row) * 576 + c0 + g * 8));
    }
    __syncthreads();
#pragma unroll
    for (int it = 0; it < 2; ++it) {
        int idx = tid + it * 256;  // 512 tasks: 64 c x 8 key-granules
        int c = idx >> 3, g = idx & 7;
        u16x8 v;
#pragma unroll
        for (int j = 0; j < 8; ++j) v[j] = t[g * 8 + j][c];
        *(u16x8*)(VT_g + ((long)(b * 512 + c0 + c) * S_LEN + k0 + g * 8)) = v;
    }
}

// ---------------------------------------------------------------------------
// MFMA flash attention in the 576-dim latent space (512 c + 64 rope).
// grid (32 bh, 16 pair); each block processes qt = 31-pair then qt = pair,
// so every block runs exactly 66 key-tiles (perfect balance; 512 blocks =
// exactly 2/CU). block = 256 = 4 waves.
//
// Wave-independent structure: wave w owns rows w*16..+16 for ALL 512 c.
//   O acc = 32 x f32x4 (128 regs); softmax state (m,l,alpha) fully private.
//   P transpose via wave-private LDS region (no barrier, lgkmcnt only).
//   -> only 2 barriers per key-tile (LDS reuse + DMA drain).
//
// K/VT tiles staged via global_load_lds in CONSUMPTION ORDER:
//   slot = frag_index*64 + lane  -> every ds_read_b128 hits 64 consecutive
//   16B granules = zero bank conflicts; DMA dst (uniform base + lane*16)
//   maps linearly. K slot (kb,h,q4,l15) <-> (key=h*16+l15, granule kb*4+q4);
//   VT slot (nb,q4,l15) <-> (c=nb*16+l15, key-granule q4).
// ---------------------------------------------------------------------------
__global__ __launch_bounds__(256, 2) void flash_mfma(
    const unsigned short* __restrict__ qabs,  const unsigned short* __restrict__ qrope,
    const unsigned short* __restrict__ ckv,   const unsigned short* __restrict__ krope,
    const unsigned short* __restrict__ VT_g,  unsigned short* __restrict__ attn_out)
{
    __shared__ unsigned short K_lds[32 * 576];    // 36 KB, consumption order
    __shared__ unsigned short VT_lds[512 * 32];   // 32 KB, consumption order
    __shared__ unsigned short P_lds[4][16 * 40];  // per-wave private, +8 pad

    const float scale = 0.07216878364870323f;  // 1/sqrt(192)
    const int tid = threadIdx.x;
    const int lane = tid & 63, w = tid >> 6;
    const int l15 = lane & 15, q4 = lane >> 4;
    const int bh = blockIdx.x;
    const int b = bh >> 4;

#pragma unroll 1
    for (int half = 0; half < 2; ++half) {
        const int qt = half ? blockIdx.y : 31 - blockIdx.y;
        const int q0 = qt * 64;

        // Q fragments: rows q0 + w*16 + l15, dims kb*32 + q4*8 (+j)
        s16x8 qf[18];
        {
            const unsigned short* qa = qabs + ((long)bh * S_LEN + q0 + w * 16 + l15) * 512 + q4 * 8;
#pragma unroll
            for (int kb = 0; kb < 16; ++kb) qf[kb] = *(const s16x8*)(qa + kb * 32);
            const unsigned short* qr = qrope + ((long)bh * S_LEN + q0 + w * 16 + l15) * 64 + q4 * 8;
            qf[16] = *(const s16x8*)(qr);
            qf[17] = *(const s16x8*)(qr + 32);
        }

        f32x4 O[32];
#pragma unroll
        for (int nb = 0; nb < 32; ++nb) O[nb] = (f32x4){0.f, 0.f, 0.f, 0.f};
        float m_i[4] = {-INFINITY, -INFINITY, -INFINITY, -INFINITY};
        float l_i[4] = {0.f, 0.f, 0.f, 0.f};

        const int nkt = 2 * qt + 2;
        for (int kt = 0; kt < nkt; ++kt) {
            const int k0 = kt * 32;

            // ---- B0: all waves done reading previous tile's LDS ----
            __syncthreads();

            // ---- stage K (9 DMA/thread) + VT (8 DMA/thread) ----
#pragma unroll
            for (int it = 0; it < 9; ++it) {
                const int idx = it * 256 + tid;        // slot index
                const int kb = idx >> 7, h = (idx >> 6) & 1;
                const int q4s = (idx >> 4) & 3, l15s = idx & 15;
                const int key = h * 16 + l15s;
                const int g = kb * 4 + q4s;            // dim granule 0..71
                const void* src = (g < 64)
                    ? (const void*)(ckv   + ((long)(b * S_LEN + k0 + key) * 576 + g * 8))
                    : (const void*)(krope + ((long)(b * S_LEN + k0 + key) * 64 + (g - 64) * 8));
                gl2lds16(src, (char*)K_lds + ((it * 256 + w * 64) << 4));
            }
#pragma unroll
            for (int it = 0; it < 8; ++it) {
                const int idx = it * 256 + tid;
                const int nb = idx >> 6;
                const int q4s = (idx >> 4) & 3, l15s = idx & 15;
                const int c = nb * 16 + l15s;
                const void* src = VT_g + ((long)(b * 512 + c) * S_LEN + k0 + q4s * 8);
                gl2lds16(src, (char*)VT_lds + ((it * 256 + w * 64) << 4));
            }

            // ---- B1: drain DMA (vmcnt(0) at barrier) ----
            __syncthreads();

            // ---- S-phase: my 16 rows x 32 keys ----
            f32x4 s0 = {0.f, 0.f, 0.f, 0.f}, s1 = s0;
#pragma unroll
            for (int kb = 0; kb < 18; ++kb) {
                s16x8 k0f = *(const s16x8*)&K_lds[((kb * 2 + 0) * 64 + lane) * 8];
                s16x8 k1f = *(const s16x8*)&K_lds[((kb * 2 + 1) * 64 + lane) * 8];
                s0 = __builtin_amdgcn_mfma_f32_16x16x32_bf16(qf[kb], k0f, s0, 0, 0, 0);
                s1 = __builtin_amdgcn_mfma_f32_16x16x32_bf16(qf[kb], k1f, s1, 0, 0, 0);
            }
#pragma unroll
            for (int r = 0; r < 4; ++r) { s0[r] *= scale; s1[r] *= scale; }
            if (kt >= 2 * qt) {  // diagonal tiles: causal mask
#pragma unroll
                for (int r = 0; r < 4; ++r) {
                    const int qg = q0 + w * 16 + q4 * 4 + r;
                    if (k0 + l15 > qg)      s0[r] = -INFINITY;
                    if (k0 + 16 + l15 > qg) s1[r] = -INFINITY;
                }
            }

            // ---- online softmax (private) + P write to wave-private LDS ----
            float al[4];
#pragma unroll
            for (int r = 0; r < 4; ++r) {
                float mx = fmaxf(s0[r], s1[r]);
#pragma unroll
                for (int off = 1; off < 16; off <<= 1) mx = fmaxf(mx, __shfl_xor(mx, off, 64));
                const float mn = fmaxf(m_i[r], mx);
                al[r] = __expf(m_i[r] - mn);   // first iter: exp(-inf)=0
                m_i[r] = mn;
                const float p0 = __expf(s0[r] - mn);
                const float p1 = __expf(s1[r] - mn);
                float ps = p0 + p1;
#pragma unroll
                for (int off = 1; off < 16; off <<= 1) ps += __shfl_xor(ps, off, 64);
                l_i[r] = l_i[r] * al[r] + ps;
                P_lds[w][(q4 * 4 + r) * 40 + l15]      = f2b(p0);
                P_lds[w][(q4 * 4 + r) * 40 + 16 + l15] = f2b(p1);
            }

            // ---- rescale O (skip when all alpha == 1) ----
            const float alm = al[0] * al[1] * al[2] * al[3];
            if (__any(alm != 1.0f)) {
#pragma unroll
                for (int nb = 0; nb < 32; ++nb)
#pragma unroll
                    for (int r = 0; r < 4; ++r) O[nb][r] *= al[r];
            }

            // ---- PV-phase: my 16 rows x all 512 c (wave-private P) ----
            s16x8 pf = *(const s16x8*)&P_lds[w][l15 * 40 + q4 * 8];
#pragma unroll
            for (int nb = 0; nb < 32; ++nb) {
                s16x8 vf = *(const s16x8*)&VT_lds[(nb * 64 + lane) * 8];
                O[nb] = __builtin_amdgcn_mfma_f32_16x16x32_bf16(pf, vf, O[nb], 0, 0, 0);
            }
        }

        // ---- epilogue: O /= l, store bf16 (all state private) ----
        float inv[4];
#pragma unroll
        for (int r = 0; r < 4; ++r) inv[r] = 1.0f / l_i[r];
#pragma unroll
        for (int r = 0; r < 4; ++r) {
            const long rowbase = ((long)bh * S_LEN + q0 + w * 16 + q4 * 4 + r) * 512;
#pragma unroll
            for (int nb = 0; nb < 32; ++nb)
                attn_out[rowbase + nb * 16 + l15] = f2b(O[nb][r] * inv[r]);
        }
    }
}

// ---------------------------------------------------------------------------
extern "C" void kernel_launch(void* const* d_in, const int* in_sizes, int n_in,
                              void* d_out, int out_size, void* d_ws, size_t ws_size,
                              hipStream_t stream)
{
    (void)in_sizes; (void)n_in; (void)out_size; (void)ws_size;
    const float* hs_f       = (const float*)d_in[0];
    const int*   pos        = (const int*)d_in[1];
    // d_in[2] = attention_mask (causal, recomputed analytically) - unused
    const float* Wq_down_f  = (const float*)d_in[3];
    const float* q_ln_w_f   = (const float*)d_in[4];
    const float* Wq_up_f    = (const float*)d_in[5];
    const float* Wkv_down_f = (const float*)d_in[6];
    const float* Wkv_up_f   = (const float*)d_in[7];
    const float* Wo_f       = (const float*)d_in[8];
    float* out = (float*)d_out;

    // workspace layout (bf16 elements). out2 aliases q (dead after step 7).
    unsigned short* ws    = (unsigned short*)d_ws;
    unsigned short* ql    = ws;                        // 4096*1536
    unsigned short* q     = ql    + 4096L * 1536;      // 4096*3072
    unsigned short* out2  = q;                         // 4096*2048 (alias)
    unsigned short* ckv   = q     + 4096L * 3072;      // 4096*576
    unsigned short* krope = ckv   + 4096L * 576;       // 4096*64
    unsigned short* qrope = krope + 4096L * 64;        // 32*2048*64
    unsigned short* qabsT = qrope + 32L * 2048 * 64;   // 16*512*128
    unsigned short* qabs  = qabsT + 16L * 512 * 128;   // 32*2048*512
    unsigned short* attno = qabs  + 32L * 2048 * 512;  // 32*2048*512
    unsigned short* hs    = attno + 32L * 2048 * 512;  // 4096*2048
    unsigned short* Wqd   = hs    + 4096L * 2048;      // 1536*2048
    unsigned short* qlnw  = Wqd   + 1536L * 2048;      // 1536
    unsigned short* Wqu   = qlnw  + 1536;              // 3072*1536
    unsigned short* Wkvd  = Wqu   + 3072L * 1536;      // 576*2048
    unsigned short* Wkvu  = Wkvd  + 576L * 2048;       // 16*256*512
    unsigned short* Wob   = Wkvu  + 16L * 256 * 512;   // 2048*2048
    unsigned short* VTg   = Wob   + 2048L * 2048;      // 2*512*2048

    // 0) fp32 -> bf16 input conversion
    f32_to_bf16<<<4096, 256, 0, stream>>>(hs_f,       hs,   4096L * 2048);
    f32_to_bf16<<<3072, 256, 0, stream>>>(Wq_down_f,  Wqd,  1536L * 2048);
    f32_to_bf16<<<2,    256, 0, stream>>>(q_ln_w_f,   qlnw, 1536L);
    f32_to_bf16<<<4096, 256, 0, stream>>>(Wq_up_f,    Wqu,  3072L * 1536);
    f32_to_bf16<<<1152, 256, 0, stream>>>(Wkv_down_f, Wkvd, 576L * 2048);
    f32_to_bf16<<<2048, 256, 0, stream>>>(Wkv_up_f,   Wkvu, 16L * 256 * 512);
    f32_to_bf16<<<4096, 256, 0, stream>>>(Wo_f,       Wob,  2048L * 2048);

    // 1) ql = hs @ Wq_down^T   (4096x1536, K=2048)
    gemm128<unsigned short><<<dim3(32, 12, 1), 256, 0, stream>>>(hs, Wqd, ql,
        2048, 2048, 2048, 1536, 1536, 0, 0, 0, 0, 0, 0);
    // 2) RMSNorm(ql)
    rmsnorm_k<<<4096, 256, 0, stream>>>(ql, qlnw);
    // 3) q = ql @ Wq_up^T      (4096x3072, K=1536)
    gemm128<unsigned short><<<dim3(32, 24, 1), 256, 0, stream>>>(ql, Wqu, q,
        1536, 1536, 1536, 3072, 3072, 0, 0, 0, 0, 0, 0);
    // 4) ckv = hs @ Wkv_down^T (4096x576, K=2048); Nlim guards last tile
    gemm128<unsigned short><<<dim3(32, 5, 1), 256, 0, stream>>>(hs, Wkvd, ckv,
        2048, 2048, 2048, 576, 576, 0, 0, 0, 0, 0, 0);
    // 5) RoPE on q (per head) and k
    rope_k<<<4096, 512, 0, stream>>>(q, ckv, pos, qrope, krope);
    // 5b) VT_g[b][c][key] = ckv[b][key][c]
    transpose_ckv<<<dim3(32, 8, 2), 256, 0, stream>>>(ckv, VTg);
    // 6) transpose q_absorb -> (h, c, n)
    transpose_qabsorb<<<4096, 256, 0, stream>>>(Wkvu, qabsT);
    // 7) q_abs[b,h] = q_nope[b,h] @ q_absorbT[h]^T  (2048x512, K=128), batched 32
    gemm128<unsigned short><<<dim3(16, 4, 32), 256, 0, stream>>>(q, qabsT, qabs,
        128, 3072, 128, 512, 512,
        2048L * 3072, 192, 0, 512L * 128, 16L * 2048 * 512, 2048L * 512);
    // 8) MFMA flash attention -> attn_out (B,NH,S,512)
    flash_mfma<<<dim3(32, 16, 1), 256, 0, stream>>>(qabs, qrope, ckv, krope, VTg, attno);
    // 9) out2 = attn_out @ out_absorb^T per head (2048x128, K=512), batched 32
    gemm128<unsigned short><<<dim3(16, 1, 32), 256, 0, stream>>>(attno, Wkvu + 128L * 512, out2,
        512, 512, 512, 2048, 128,
        16L * 2048 * 512, 2048L * 512, 0, 256L * 512, 2048L * 2048, 128);
    // 10) out = out2 @ Wo^T    (4096x2048, K=2048), fp32 output
    gemm128<float><<<dim3(32, 16, 1), 256, 0, stream>>>(out2, Wob, out,
        2048, 2048, 2048, 2048, 2048, 0, 0, 0, 0, 0, 0);
}